// Round 1
// baseline (746.917 us; speedup 1.0000x reference)
//
#include <hip/hip_runtime.h>
#include <math.h>

#define BB 64
#define TT 128
#define NN 64
#define HH 64
#define EE 128
#define KK 7
#define GG 192  // 3*H

__device__ __forceinline__ float sigmoidf_(float x){ return 1.f/(1.f+expf(-x)); }

// Conv1d (N->N, K=7, pad same) + SELU. Writes c_nt [B,N,T] and c_btn [B,T,N].
__global__ void conv_selu_kernel(const float* __restrict__ x, const float* __restrict__ w,
                                 const float* __restrict__ bias,
                                 float* __restrict__ c_nt, float* __restrict__ c_btn) {
  const int o = blockIdx.x, b = blockIdx.y, t = threadIdx.x;  // 128 threads = t
  __shared__ float xs[NN * 129];   // [n][t], +1 pad
  __shared__ float ws[NN * KK];
  for (int idx = t; idx < TT * NN; idx += 128) {
    int tt = idx >> 6, nn = idx & 63;
    xs[nn * 129 + tt] = x[(size_t)(b * TT + tt) * NN + nn];
  }
  for (int idx = t; idx < NN * KK; idx += 128) ws[idx] = w[o * NN * KK + idx];
  __syncthreads();
  float acc = bias[o];
  #pragma unroll
  for (int k = 0; k < KK; ++k) {
    int tt = t + k - 3;
    if (tt >= 0 && tt < TT) {
      #pragma unroll 8
      for (int i = 0; i < NN; ++i) acc += xs[i * 129 + tt] * ws[i * KK + k];
    }
  }
  const float alpha = 1.6732632423543772f, scale = 1.0507009873554805f;
  float r = acc > 0.f ? scale * acc : scale * alpha * expm1f(acc);
  c_nt[((size_t)b * NN + o) * TT + t] = r;
  c_btn[((size_t)b * TT + t) * NN + o] = r;
}

// Generic row-parallel linear: out[m, col] = act(bias[col] + sum_k in[m,k]*W[col*w_stride + w_off + k])
template<int NCOL, int KD, int ACT>
__global__ void linear_kernel(const float* __restrict__ in, int in_stride,
                              const float* __restrict__ W, int w_stride, int w_off,
                              const float* __restrict__ bias,
                              float* __restrict__ out, int out_stride) {
  const int m = blockIdx.x, col = threadIdx.x;  // NCOL threads
  __shared__ float ins[KD];
  for (int k = col; k < KD; k += NCOL) ins[k] = in[(size_t)m * in_stride + k];
  __syncthreads();
  const float* wr = W + (size_t)col * w_stride + w_off;
  float acc = bias ? bias[col] : 0.f;
  #pragma unroll 8
  for (int k = 0; k < KD; ++k) acc += ins[k] * wr[k];
  if (ACT) acc = fmaxf(acc, 0.f);
  out[(size_t)m * out_stride + col] = acc;
}

// GAT: per (b,i): e_j = Wa . lrelu(s1[b,i,:]+s2[b,j,:]+bw) + ba; softmax_j; h_mp = sigmoid(att @ v)
__global__ void gat_kernel(const float* __restrict__ s1, const float* __restrict__ s2,
                           const float* __restrict__ bw, const float* __restrict__ Wa,
                           const float* __restrict__ ba, const float* __restrict__ c_nt,
                           float* __restrict__ h_cat) {
  const int i = blockIdx.x, b = blockIdx.y, tid = threadIdx.x;  // 128 threads
  __shared__ float s1i[EE], bws[EE], was[EE], att[NN];
  s1i[tid] = s1[((size_t)b * NN + i) * EE + tid];
  bws[tid] = bw[tid];
  was[tid] = Wa[tid];
  __syncthreads();
  if (tid < NN) {  // wave 0 only (full 64-lane wave)
    const float* s2r = s2 + ((size_t)b * NN + tid) * EE;
    float acc = 0.f;
    #pragma unroll 8
    for (int e = 0; e < EE; ++e) {
      float wv = s1i[e] + s2r[e] + bws[e];
      wv = wv > 0.f ? wv : 0.2f * wv;
      acc += was[e] * wv;
    }
    float ej = acc + ba[0];
    float mx = ej;
    for (int off = 32; off >= 1; off >>= 1) mx = fmaxf(mx, __shfl_xor(mx, off));
    float ex = expf(ej - mx);
    float sm = ex;
    for (int off = 32; off >= 1; off >>= 1) sm += __shfl_xor(sm, off);
    att[tid] = ex / sm;
  }
  __syncthreads();
  float acc = 0.f;
  #pragma unroll 8
  for (int j = 0; j < NN; ++j) acc += att[j] * c_nt[((size_t)b * NN + j) * TT + tid];
  // h_mp[b,i,t] -> h_cat[b, t, HH + i]
  h_cat[((size_t)b * TT + tid) * (HH + NN) + HH + i] = sigmoidf_(acc);
}

// GRU over time: one block per batch, 192 threads = 3H gate lanes.
// gi precomputed [B,T,192]. h kept in LDS. Whh staged transposed (stride 193).
__global__ void gru_kernel(const float* __restrict__ gi, const float* __restrict__ Whh,
                           const float* __restrict__ bhh,
                           float* __restrict__ out, int out_stride) {
  const int b = blockIdx.x, g = threadIdx.x;  // 192 threads
  __shared__ float whh_t[HH * 193];  // [k][g] stride 193 (conflict-free both ways)
  __shared__ float h[HH];
  __shared__ float u[GG], v[GG];
  for (int k = 0; k < HH; ++k) whh_t[k * 193 + g] = Whh[g * HH + k];
  const float bh = bhh[g];
  if (g < HH) h[g] = 0.f;
  __syncthreads();
  const float* gib = gi + (size_t)b * TT * GG;
  for (int t = 0; t < TT; ++t) {
    float a0 = 0.f, a1 = 0.f, a2 = 0.f, a3 = 0.f;
    #pragma unroll
    for (int k = 0; k < HH; k += 4) {
      a0 += h[k]     * whh_t[(k)     * 193 + g];
      a1 += h[k + 1] * whh_t[(k + 1) * 193 + g];
      a2 += h[k + 2] * whh_t[(k + 2) * 193 + g];
      a3 += h[k + 3] * whh_t[(k + 3) * 193 + g];
    }
    u[g] = gib[t * GG + g];
    v[g] = (a0 + a1) + (a2 + a3) + bh;
    __syncthreads();
    float hn = 0.f;
    if (g < HH) {
      float r  = sigmoidf_(u[g] + v[g]);
      float z  = sigmoidf_(u[HH + g] + v[HH + g]);
      float nn = tanhf(u[2 * HH + g] + r * v[2 * HH + g]);
      hn = (1.f - z) * nn + z * h[g];
    }
    __syncthreads();
    if (g < HH) {
      h[g] = hn;
      out[((size_t)b * TT + t) * out_stride + g] = hn;
    }
    __syncthreads();
  }
}

extern "C" void kernel_launch(void* const* d_in, const int* in_sizes, int n_in,
                              void* d_out, int out_size, void* d_ws, size_t ws_size,
                              hipStream_t stream) {
  const float* x      = (const float*)d_in[0];
  // d_in[1] = y (unused in eval forward)
  const float* conv_w = (const float*)d_in[2];
  const float* conv_b = (const float*)d_in[3];
  const float* We_ih  = (const float*)d_in[4];
  const float* We_hh  = (const float*)d_in[5];
  const float* be_ih  = (const float*)d_in[6];
  const float* be_hh  = (const float*)d_in[7];
  const float* Ww     = (const float*)d_in[8];
  const float* bw     = (const float*)d_in[9];
  const float* Wa     = (const float*)d_in[10];
  const float* ba     = (const float*)d_in[11];
  const float* Wm_ih  = (const float*)d_in[12];
  const float* Wm_hh  = (const float*)d_in[13];
  const float* bm_ih  = (const float*)d_in[14];
  const float* bm_hh  = (const float*)d_in[15];
  const float* Wd_ih  = (const float*)d_in[16];
  const float* Wd_hh  = (const float*)d_in[17];
  const float* bd_ih  = (const float*)d_in[18];
  const float* bd_hh  = (const float*)d_in[19];
  const float* W_dec  = (const float*)d_in[20];
  const float* b_dec  = (const float*)d_in[21];
  const float* W_p1   = (const float*)d_in[22];
  const float* b_p1   = (const float*)d_in[23];
  const float* W_p2   = (const float*)d_in[24];
  const float* b_p2   = (const float*)d_in[25];
  float* out = (float*)d_out;

  float* wsf   = (float*)d_ws;
  float* c_nt  = wsf;                 // B*N*T   = 524288
  float* c_btn = c_nt  + 524288;      // B*T*N   = 524288
  float* s1    = c_btn + 524288;      // B*N*E   = 524288
  float* s2    = s1    + 524288;      // B*N*E   = 524288
  float* h_cat = s2    + 524288;      // B*T*(H+N) = 1048576
  float* gi    = h_cat + 1048576;     // B*T*3H  = 1572864
  float* h_enc = gi    + 1572864;     // B*T*H   = 524288
  float* h_dec = h_enc + 524288;      // B*T*H   = 524288
  float* ptmp  = h_dec + 524288;      // B*N     = 4096

  // 1. conv + selu
  conv_selu_kernel<<<dim3(NN, BB), 128, 0, stream>>>(x, conv_w, conv_b, c_nt, c_btn);
  // 2. GAT score projections s1/s2 (v = c_nt viewed as [B*N, T])
  linear_kernel<EE, TT, 0><<<BB * NN, EE, 0, stream>>>(c_nt, TT, Ww, 2 * TT, 0,  nullptr, s1, EE);
  linear_kernel<EE, TT, 0><<<BB * NN, EE, 0, stream>>>(c_nt, TT, Ww, 2 * TT, TT, nullptr, s2, EE);
  // 3. GAT attention + h_mp -> h_cat[:, :, 64:128]
  gat_kernel<<<dim3(NN, BB), 128, 0, stream>>>(s1, s2, bw, Wa, ba, c_nt, h_cat);
  // 4. rnn_enc: gi then GRU -> h_cat[:, :, 0:64]
  linear_kernel<GG, NN, 0><<<BB * TT, GG, 0, stream>>>(c_btn, NN, We_ih, NN, 0, be_ih, gi, GG);
  gru_kernel<<<BB, GG, 0, stream>>>(gi, We_hh, be_hh, h_cat, HH + NN);
  // 5. encoder GRU on h_cat
  linear_kernel<GG, HH + NN, 0><<<BB * TT, GG, 0, stream>>>(h_cat, HH + NN, Wm_ih, HH + NN, 0, bm_ih, gi, GG);
  gru_kernel<<<BB, GG, 0, stream>>>(gi, Wm_hh, bm_hh, h_enc, HH);
  // 6. decoder GRU
  linear_kernel<GG, HH, 0><<<BB * TT, GG, 0, stream>>>(h_enc, HH, Wd_ih, HH, 0, bd_ih, gi, GG);
  gru_kernel<<<BB, GG, 0, stream>>>(gi, Wd_hh, bd_hh, h_dec, HH);
  // 7. recon head -> out[0 : B*T*N]
  linear_kernel<NN, HH, 0><<<BB * TT, NN, 0, stream>>>(h_dec, HH, W_dec, HH, 0, b_dec, out, NN);
  // 8. pred head (row t=0) -> out[B*T*N : B*T*N + B*N]
  linear_kernel<NN, HH, 1><<<BB, NN, 0, stream>>>(h_dec, TT * HH, W_p1, HH, 0, b_p1, ptmp, NN);
  linear_kernel<NN, HH, 0><<<BB, NN, 0, stream>>>(ptmp, NN, W_p2, HH, 0, b_p2, out + BB * TT * NN, NN);
}

// Round 2
// 542.013 us; speedup vs baseline: 1.3780x; 1.3780x over previous
//
#include <hip/hip_runtime.h>
#include <math.h>

#define BB 64
#define TT 128
#define NN 64
#define HH 64
#define EE 128
#define KK 7
#define GG 192  // 3*H

__device__ __forceinline__ float sigmoidf_(float x){ return 1.f/(1.f+expf(-x)); }

// Conv1d (N->N, K=7, pad same) + SELU. 8 output channels per block.
// grid (8, B), 128 threads (= t). Writes c_nt [B,N,T] and c_btn [B,T,N].
__global__ void conv_selu_kernel(const float* __restrict__ x, const float* __restrict__ w,
                                 const float* __restrict__ bias,
                                 float* __restrict__ c_nt, float* __restrict__ c_btn) {
  const int og = blockIdx.x, b = blockIdx.y, t = threadIdx.x;
  const int o0 = og * 8;
  __shared__ __align__(16) float xs[NN][TT + 1];      // [n][t]
  __shared__ __align__(16) float ws[NN * KK][8];      // [i*7+k][oo]
  for (int idx = t; idx < TT * NN; idx += 128) {
    int tt = idx >> 6, nn = idx & 63;
    xs[nn][tt] = x[(size_t)(b * TT + tt) * NN + nn];
  }
  for (int idx = t; idx < NN * KK * 8; idx += 128) {
    int oo = idx & 7, ik = idx >> 3;
    ws[ik][oo] = w[(size_t)(o0 + oo) * (NN * KK) + ik];
  }
  __syncthreads();
  float acc[8];
  #pragma unroll
  for (int oo = 0; oo < 8; ++oo) acc[oo] = bias[o0 + oo];
  for (int i = 0; i < NN; ++i) {
    #pragma unroll
    for (int k = 0; k < KK; ++k) {
      int tt = t + k - 3;
      if (tt >= 0 && tt < TT) {
        float xv = xs[i][tt];
        const float* wp = &ws[i * KK + k][0];
        float4 w0 = *(const float4*)wp;
        float4 w1 = *(const float4*)(wp + 4);
        acc[0] += xv * w0.x; acc[1] += xv * w0.y; acc[2] += xv * w0.z; acc[3] += xv * w0.w;
        acc[4] += xv * w1.x; acc[5] += xv * w1.y; acc[6] += xv * w1.z; acc[7] += xv * w1.w;
      }
    }
  }
  const float alpha = 1.6732632423543772f, scale = 1.0507009873554805f;
  #pragma unroll
  for (int oo = 0; oo < 8; ++oo) {
    float a = acc[oo];
    float r = a > 0.f ? scale * a : scale * alpha * expm1f(a);
    int o = o0 + oo;
    c_nt[((size_t)b * NN + o) * TT + t] = r;
    c_btn[((size_t)b * TT + t) * NN + o] = r;
  }
}

// Tiled linear: out[m0+r, col] = act(bias[col] + sum_k in[m0+r,k] * W[col*w_stride + w_off + k])
// TM rows per block, NCOL threads (one per output col). Input tile staged in LDS.
template<int NCOL, int KD, int TM, int ACT>
__global__ void linear_tiled(const float* __restrict__ in, int in_stride,
                             const float* __restrict__ W, int w_stride, int w_off,
                             const float* __restrict__ bias,
                             float* __restrict__ out, int out_stride) {
  const int m0 = blockIdx.x * TM, col = threadIdx.x;
  __shared__ __align__(16) float ins[TM][KD];
  for (int idx = col; idx < TM * KD; idx += NCOL) {
    int r = idx / KD, k = idx - r * KD;
    ins[r][k] = in[(size_t)(m0 + r) * in_stride + k];
  }
  __syncthreads();
  const float* wr = W + (size_t)col * w_stride + w_off;
  float bv = bias ? bias[col] : 0.f;
  float acc[TM];
  #pragma unroll
  for (int r = 0; r < TM; ++r) acc[r] = bv;
  #pragma unroll 2
  for (int k = 0; k < KD; k += 4) {
    float4 wv = *(const float4*)(wr + k);
    #pragma unroll
    for (int r = 0; r < TM; ++r) {
      float4 iv = *(const float4*)&ins[r][k];
      acc[r] += iv.x * wv.x + iv.y * wv.y + iv.z * wv.z + iv.w * wv.w;
    }
  }
  #pragma unroll
  for (int r = 0; r < TM; ++r) {
    float a = ACT ? fmaxf(acc[r], 0.f) : acc[r];
    out[(size_t)(m0 + r) * out_stride + col] = a;
  }
}

// GAT: per (b,i): e_j = Wa . lrelu(s1[b,i,:]+s2[b,j,:]+bw) + ba; softmax_j; h_mp = sigmoid(att @ v)
__global__ void gat_kernel(const float* __restrict__ s1, const float* __restrict__ s2,
                           const float* __restrict__ bw, const float* __restrict__ Wa,
                           const float* __restrict__ ba, const float* __restrict__ c_nt,
                           float* __restrict__ h_cat) {
  const int i = blockIdx.x, b = blockIdx.y, tid = threadIdx.x;  // 128 threads
  __shared__ float s2s[NN][EE + 1];
  __shared__ float s1b[EE], was[EE], att[NN];
  for (int idx = tid; idx < NN * EE; idx += 128) {
    int r = idx >> 7, e = idx & 127;
    s2s[r][e] = s2[((size_t)b * NN + r) * EE + e];
  }
  s1b[tid] = s1[((size_t)b * NN + i) * EE + tid] + bw[tid];
  was[tid] = Wa[tid];
  __syncthreads();
  if (tid < NN) {  // wave 0 (full 64-lane wave)
    float acc = 0.f;
    #pragma unroll 8
    for (int e = 0; e < EE; ++e) {
      float wv = s1b[e] + s2s[tid][e];
      wv = wv > 0.f ? wv : 0.2f * wv;
      acc += was[e] * wv;
    }
    float ej = acc + ba[0];
    float mx = ej;
    for (int off = 32; off >= 1; off >>= 1) mx = fmaxf(mx, __shfl_xor(mx, off));
    float ex = expf(ej - mx);
    float sm = ex;
    for (int off = 32; off >= 1; off >>= 1) sm += __shfl_xor(sm, off);
    att[tid] = ex / sm;
  }
  __syncthreads();
  float acc = 0.f;
  #pragma unroll 8
  for (int j = 0; j < NN; ++j) acc += att[j] * c_nt[((size_t)b * NN + j) * TT + tid];
  h_cat[((size_t)b * TT + tid) * (HH + NN) + HH + i] = sigmoidf_(acc);
}

// GRU over time: one block = one batch = ONE 64-lane wave. Thread g owns hidden unit g.
// Whh rows g / g+64 / g+128 live in 192 VGPRs. h broadcast via LDS float4 reads.
__global__ __launch_bounds__(64, 1)
void gru_wave_kernel(const float* __restrict__ gi, const float* __restrict__ Whh,
                     const float* __restrict__ bhh,
                     float* __restrict__ out, int out_stride) {
  const int b = blockIdx.x, g = threadIdx.x;  // 64 threads
  __shared__ __align__(16) float hs[HH];
  float wr[HH], wz[HH], wn[HH];
  const float4* Wr4 = (const float4*)(Whh + (size_t)g * HH);
  const float4* Wz4 = (const float4*)(Whh + (size_t)(g + HH) * HH);
  const float4* Wn4 = (const float4*)(Whh + (size_t)(g + 2 * HH) * HH);
  #pragma unroll
  for (int i = 0; i < HH / 4; ++i) {
    float4 a = Wr4[i]; wr[4*i] = a.x; wr[4*i+1] = a.y; wr[4*i+2] = a.z; wr[4*i+3] = a.w;
    float4 c = Wz4[i]; wz[4*i] = c.x; wz[4*i+1] = c.y; wz[4*i+2] = c.z; wz[4*i+3] = c.w;
    float4 d = Wn4[i]; wn[4*i] = d.x; wn[4*i+1] = d.y; wn[4*i+2] = d.z; wn[4*i+3] = d.w;
  }
  const float br = bhh[g], bz = bhh[g + HH], bn = bhh[g + 2 * HH];
  float h = 0.f;
  hs[g] = 0.f;
  __syncthreads();
  const float* gib = gi + (size_t)b * TT * GG + g;
  float gr = gib[0], gz = gib[HH], gn = gib[2 * HH];
  for (int t = 0; t < TT; ++t) {
    float grn = 0.f, gzn = 0.f, gnn = 0.f;
    if (t + 1 < TT) {
      const float* p = gib + (size_t)(t + 1) * GG;
      grn = p[0]; gzn = p[HH]; gnn = p[2 * HH];
    }
    float ar = br, az = bz, an = bn;
    #pragma unroll
    for (int i = 0; i < HH / 4; ++i) {
      float4 hv = *(const float4*)&hs[4 * i];
      ar += hv.x * wr[4*i] + hv.y * wr[4*i+1] + hv.z * wr[4*i+2] + hv.w * wr[4*i+3];
      az += hv.x * wz[4*i] + hv.y * wz[4*i+1] + hv.z * wz[4*i+2] + hv.w * wz[4*i+3];
      an += hv.x * wn[4*i] + hv.y * wn[4*i+1] + hv.z * wn[4*i+2] + hv.w * wn[4*i+3];
    }
    float r = sigmoidf_(gr + ar);
    float z = sigmoidf_(gz + az);
    float n = tanhf(gn + r * an);
    h = (1.f - z) * n + z * h;
    out[((size_t)b * TT + t) * out_stride + g] = h;
    __syncthreads();          // all lanes done reading old hs (wave-order) ; make write visible
    hs[g] = h;
    __syncthreads();
    gr = grn; gz = gzn; gn = gnn;
  }
}

extern "C" void kernel_launch(void* const* d_in, const int* in_sizes, int n_in,
                              void* d_out, int out_size, void* d_ws, size_t ws_size,
                              hipStream_t stream) {
  const float* x      = (const float*)d_in[0];
  const float* conv_w = (const float*)d_in[2];
  const float* conv_b = (const float*)d_in[3];
  const float* We_ih  = (const float*)d_in[4];
  const float* We_hh  = (const float*)d_in[5];
  const float* be_ih  = (const float*)d_in[6];
  const float* be_hh  = (const float*)d_in[7];
  const float* Ww     = (const float*)d_in[8];
  const float* bw     = (const float*)d_in[9];
  const float* Wa     = (const float*)d_in[10];
  const float* ba     = (const float*)d_in[11];
  const float* Wm_ih  = (const float*)d_in[12];
  const float* Wm_hh  = (const float*)d_in[13];
  const float* bm_ih  = (const float*)d_in[14];
  const float* bm_hh  = (const float*)d_in[15];
  const float* Wd_ih  = (const float*)d_in[16];
  const float* Wd_hh  = (const float*)d_in[17];
  const float* bd_ih  = (const float*)d_in[18];
  const float* bd_hh  = (const float*)d_in[19];
  const float* W_dec  = (const float*)d_in[20];
  const float* b_dec  = (const float*)d_in[21];
  const float* W_p1   = (const float*)d_in[22];
  const float* b_p1   = (const float*)d_in[23];
  const float* W_p2   = (const float*)d_in[24];
  const float* b_p2   = (const float*)d_in[25];
  float* out = (float*)d_out;

  float* wsf   = (float*)d_ws;
  float* c_nt  = wsf;                 // B*N*T   = 524288
  float* c_btn = c_nt  + 524288;      // B*T*N   = 524288
  float* s1    = c_btn + 524288;      // B*N*E   = 524288
  float* s2    = s1    + 524288;      // B*N*E   = 524288
  float* h_cat = s2    + 524288;      // B*T*(H+N) = 1048576
  float* gi    = h_cat + 1048576;     // B*T*3H  = 1572864
  float* h_enc = gi    + 1572864;     // B*T*H   = 524288
  float* h_dec = h_enc + 524288;      // B*T*H   = 524288
  float* ptmp  = h_dec + 524288;      // B*N     = 4096

  // 1. conv + selu
  conv_selu_kernel<<<dim3(8, BB), 128, 0, stream>>>(x, conv_w, conv_b, c_nt, c_btn);
  // 2. GAT score projections (v = c_nt as [B*N, T])
  linear_tiled<EE, TT, 16, 0><<<BB * NN / 16, EE, 0, stream>>>(c_nt, TT, Ww, 2 * TT, 0,  nullptr, s1, EE);
  linear_tiled<EE, TT, 16, 0><<<BB * NN / 16, EE, 0, stream>>>(c_nt, TT, Ww, 2 * TT, TT, nullptr, s2, EE);
  // 3. GAT attention -> h_cat[:, :, 64:128]
  gat_kernel<<<dim3(NN, BB), 128, 0, stream>>>(s1, s2, bw, Wa, ba, c_nt, h_cat);
  // 4. rnn_enc
  linear_tiled<GG, NN, 16, 0><<<BB * TT / 16, GG, 0, stream>>>(c_btn, NN, We_ih, NN, 0, be_ih, gi, GG);
  gru_wave_kernel<<<BB, 64, 0, stream>>>(gi, We_hh, be_hh, h_cat, HH + NN);
  // 5. encoder GRU
  linear_tiled<GG, HH + NN, 16, 0><<<BB * TT / 16, GG, 0, stream>>>(h_cat, HH + NN, Wm_ih, HH + NN, 0, bm_ih, gi, GG);
  gru_wave_kernel<<<BB, 64, 0, stream>>>(gi, Wm_hh, bm_hh, h_enc, HH);
  // 6. decoder GRU
  linear_tiled<GG, HH, 16, 0><<<BB * TT / 16, GG, 0, stream>>>(h_enc, HH, Wd_ih, HH, 0, bd_ih, gi, GG);
  gru_wave_kernel<<<BB, 64, 0, stream>>>(gi, Wd_hh, bd_hh, h_dec, HH);
  // 7. recon head
  linear_tiled<NN, HH, 16, 0><<<BB * TT / 16, NN, 0, stream>>>(h_dec, HH, W_dec, HH, 0, b_dec, out, NN);
  // 8. pred head (row t=0)
  linear_tiled<NN, HH, 16, 1><<<BB / 16, NN, 0, stream>>>(h_dec, TT * HH, W_p1, HH, 0, b_p1, ptmp, NN);
  linear_tiled<NN, HH, 16, 0><<<BB / 16, NN, 0, stream>>>(ptmp, NN, W_p2, HH, 0, b_p2, out + BB * TT * NN, NN);
}

// Round 3
// 397.063 us; speedup vs baseline: 1.8811x; 1.3651x over previous
//
#include <hip/hip_runtime.h>
#include <math.h>

#define BB 64
#define TT 128
#define NN 64
#define HH 64
#define EE 128
#define KK 7
#define GG 192  // 3*H

__device__ __forceinline__ float sigmoidf_(float x){ return 1.f/(1.f+expf(-x)); }
// fast variants for the GRU inner loop (threshold 4.1e-3 >> __expf error)
__device__ __forceinline__ float fsig_(float x){ return __frcp_rn(1.f + __expf(-x)); }
__device__ __forceinline__ float ftanh_(float x){ return 2.f * __frcp_rn(1.f + __expf(-2.f * x)) - 1.f; }
__device__ __forceinline__ float bcast_(float v, int lane){
  return __uint_as_float(__builtin_amdgcn_readlane(__float_as_uint(v), lane));
}

// Conv1d (N->N, K=7, pad same) + SELU. 8 output channels per block.
// grid (8, B), 128 threads (= t). Writes c_nt [B,N,T] and c_btn [B,T,N].
__global__ void conv_selu_kernel(const float* __restrict__ x, const float* __restrict__ w,
                                 const float* __restrict__ bias,
                                 float* __restrict__ c_nt, float* __restrict__ c_btn) {
  const int og = blockIdx.x, b = blockIdx.y, t = threadIdx.x;
  const int o0 = og * 8;
  __shared__ __align__(16) float xs[NN][TT + 1];      // [n][t]
  __shared__ __align__(16) float ws[NN * KK][8];      // [i*7+k][oo]
  for (int idx = t; idx < TT * NN; idx += 128) {
    int tt = idx >> 6, nn = idx & 63;
    xs[nn][tt] = x[(size_t)(b * TT + tt) * NN + nn];
  }
  for (int idx = t; idx < NN * KK * 8; idx += 128) {
    int oo = idx & 7, ik = idx >> 3;
    ws[ik][oo] = w[(size_t)(o0 + oo) * (NN * KK) + ik];
  }
  __syncthreads();
  float acc[8];
  #pragma unroll
  for (int oo = 0; oo < 8; ++oo) acc[oo] = bias[o0 + oo];
  for (int i = 0; i < NN; ++i) {
    #pragma unroll
    for (int k = 0; k < KK; ++k) {
      int tt = t + k - 3;
      if (tt >= 0 && tt < TT) {
        float xv = xs[i][tt];
        const float* wp = &ws[i * KK + k][0];
        float4 w0 = *(const float4*)wp;
        float4 w1 = *(const float4*)(wp + 4);
        acc[0] += xv * w0.x; acc[1] += xv * w0.y; acc[2] += xv * w0.z; acc[3] += xv * w0.w;
        acc[4] += xv * w1.x; acc[5] += xv * w1.y; acc[6] += xv * w1.z; acc[7] += xv * w1.w;
      }
    }
  }
  const float alpha = 1.6732632423543772f, scale = 1.0507009873554805f;
  #pragma unroll
  for (int oo = 0; oo < 8; ++oo) {
    float a = acc[oo];
    float r = a > 0.f ? scale * a : scale * alpha * expm1f(a);
    int o = o0 + oo;
    c_nt[((size_t)b * NN + o) * TT + t] = r;
    c_btn[((size_t)b * TT + t) * NN + o] = r;
  }
}

// Tiled linear: out[m0+r, col] = act(bias[col] + sum_k in[m0+r,k] * W[col*w_stride + w_off + k])
template<int NCOL, int KD, int TM, int ACT>
__global__ void linear_tiled(const float* __restrict__ in, int in_stride,
                             const float* __restrict__ W, int w_stride, int w_off,
                             const float* __restrict__ bias,
                             float* __restrict__ out, int out_stride) {
  const int m0 = blockIdx.x * TM, col = threadIdx.x;
  __shared__ __align__(16) float ins[TM][KD];
  for (int idx = col; idx < TM * KD; idx += NCOL) {
    int r = idx / KD, k = idx - r * KD;
    ins[r][k] = in[(size_t)(m0 + r) * in_stride + k];
  }
  __syncthreads();
  const float* wr = W + (size_t)col * w_stride + w_off;
  float bv = bias ? bias[col] : 0.f;
  float acc[TM];
  #pragma unroll
  for (int r = 0; r < TM; ++r) acc[r] = bv;
  #pragma unroll 2
  for (int k = 0; k < KD; k += 4) {
    float4 wv = *(const float4*)(wr + k);
    #pragma unroll
    for (int r = 0; r < TM; ++r) {
      float4 iv = *(const float4*)&ins[r][k];
      acc[r] += iv.x * wv.x + iv.y * wv.y + iv.z * wv.z + iv.w * wv.w;
    }
  }
  #pragma unroll
  for (int r = 0; r < TM; ++r) {
    float a = ACT ? fmaxf(acc[r], 0.f) : acc[r];
    out[(size_t)(m0 + r) * out_stride + col] = a;
  }
}

// GAT: per (b,i): e_j = Wa . lrelu(s1[b,i,:]+s2[b,j,:]+bw) + ba; softmax_j; h_mp = sigmoid(att @ v)
__global__ void gat_kernel(const float* __restrict__ s1, const float* __restrict__ s2,
                           const float* __restrict__ bw, const float* __restrict__ Wa,
                           const float* __restrict__ ba, const float* __restrict__ c_nt,
                           float* __restrict__ h_cat) {
  const int i = blockIdx.x, b = blockIdx.y, tid = threadIdx.x;  // 128 threads
  __shared__ float s2s[NN][EE + 1];
  __shared__ float s1b[EE], was[EE], att[NN];
  for (int idx = tid; idx < NN * EE; idx += 128) {
    int r = idx >> 7, e = idx & 127;
    s2s[r][e] = s2[((size_t)b * NN + r) * EE + e];
  }
  s1b[tid] = s1[((size_t)b * NN + i) * EE + tid] + bw[tid];
  was[tid] = Wa[tid];
  __syncthreads();
  if (tid < NN) {  // wave 0 (full 64-lane wave)
    float acc = 0.f;
    #pragma unroll 8
    for (int e = 0; e < EE; ++e) {
      float wv = s1b[e] + s2s[tid][e];
      wv = wv > 0.f ? wv : 0.2f * wv;
      acc += was[e] * wv;
    }
    float ej = acc + ba[0];
    float mx = ej;
    for (int off = 32; off >= 1; off >>= 1) mx = fmaxf(mx, __shfl_xor(mx, off));
    float ex = expf(ej - mx);
    float sm = ex;
    for (int off = 32; off >= 1; off >>= 1) sm += __shfl_xor(sm, off);
    att[tid] = ex / sm;
  }
  __syncthreads();
  float acc = 0.f;
  #pragma unroll 8
  for (int j = 0; j < NN; ++j) acc += att[j] * c_nt[((size_t)b * NN + j) * TT + tid];
  h_cat[((size_t)b * TT + tid) * (HH + NN) + HH + i] = sigmoidf_(acc);
}

// GRU over time: one block = one batch = ONE 64-lane wave. Thread g owns hidden unit g.
// Whh rows g / g+64 / g+128 in registers (AGPR/VGPR). h broadcast via v_readlane —
// NO LDS, NO barriers on the critical path.
__global__ __launch_bounds__(64, 1)
void gru_wave_kernel(const float* __restrict__ gi, const float* __restrict__ Whh,
                     const float* __restrict__ bhh,
                     float* __restrict__ out, int out_stride) {
  const int b = blockIdx.x, g = threadIdx.x;  // 64 threads
  float4 wr4[16], wz4[16], wn4[16];
  const float4* Wr4 = (const float4*)(Whh + (size_t)g * HH);
  const float4* Wz4 = (const float4*)(Whh + (size_t)(g + HH) * HH);
  const float4* Wn4 = (const float4*)(Whh + (size_t)(g + 2 * HH) * HH);
  #pragma unroll
  for (int i = 0; i < 16; ++i) { wr4[i] = Wr4[i]; wz4[i] = Wz4[i]; wn4[i] = Wn4[i]; }
  const float br = bhh[g], bz = bhh[g + HH], bn = bhh[g + 2 * HH];
  float h = 0.f;
  const float* gib = gi + (size_t)b * TT * GG + g;
  float gr = gib[0], gz = gib[HH], gn = gib[2 * HH];
  for (int t = 0; t < TT; ++t) {
    float grn = 0.f, gzn = 0.f, gnn = 0.f;
    if (t + 1 < TT) {
      const float* p = gib + (size_t)(t + 1) * GG;
      grn = p[0]; gzn = p[HH]; gnn = p[2 * HH];
    }
    // two accumulators per gate to halve dependency depth
    float ar0 = br, az0 = bz, an0 = bn, ar1 = 0.f, az1 = 0.f, an1 = 0.f;
    #pragma unroll
    for (int i = 0; i < 8; ++i) {
      float4 a = wr4[i], c = wz4[i], d = wn4[i];
      float h0 = bcast_(h, 4 * i), h1 = bcast_(h, 4 * i + 1),
            h2 = bcast_(h, 4 * i + 2), h3 = bcast_(h, 4 * i + 3);
      ar0 = fmaf(h0, a.x, fmaf(h1, a.y, fmaf(h2, a.z, fmaf(h3, a.w, ar0))));
      az0 = fmaf(h0, c.x, fmaf(h1, c.y, fmaf(h2, c.z, fmaf(h3, c.w, az0))));
      an0 = fmaf(h0, d.x, fmaf(h1, d.y, fmaf(h2, d.z, fmaf(h3, d.w, an0))));
    }
    #pragma unroll
    for (int i = 8; i < 16; ++i) {
      float4 a = wr4[i], c = wz4[i], d = wn4[i];
      float h0 = bcast_(h, 4 * i), h1 = bcast_(h, 4 * i + 1),
            h2 = bcast_(h, 4 * i + 2), h3 = bcast_(h, 4 * i + 3);
      ar1 = fmaf(h0, a.x, fmaf(h1, a.y, fmaf(h2, a.z, fmaf(h3, a.w, ar1))));
      az1 = fmaf(h0, c.x, fmaf(h1, c.y, fmaf(h2, c.z, fmaf(h3, c.w, az1))));
      an1 = fmaf(h0, d.x, fmaf(h1, d.y, fmaf(h2, d.z, fmaf(h3, d.w, an1))));
    }
    float r = fsig_(gr + ar0 + ar1);
    float z = fsig_(gz + az0 + az1);
    float n = ftanh_(gn + fmaf(r, an0 + an1, 0.f));
    h = fmaf(z, h - n, n);   // (1-z)*n + z*h
    out[((size_t)b * TT + t) * out_stride + g] = h;
    gr = grn; gz = gzn; gn = gnn;
  }
}

extern "C" void kernel_launch(void* const* d_in, const int* in_sizes, int n_in,
                              void* d_out, int out_size, void* d_ws, size_t ws_size,
                              hipStream_t stream) {
  const float* x      = (const float*)d_in[0];
  const float* conv_w = (const float*)d_in[2];
  const float* conv_b = (const float*)d_in[3];
  const float* We_ih  = (const float*)d_in[4];
  const float* We_hh  = (const float*)d_in[5];
  const float* be_ih  = (const float*)d_in[6];
  const float* be_hh  = (const float*)d_in[7];
  const float* Ww     = (const float*)d_in[8];
  const float* bw     = (const float*)d_in[9];
  const float* Wa     = (const float*)d_in[10];
  const float* ba     = (const float*)d_in[11];
  const float* Wm_ih  = (const float*)d_in[12];
  const float* Wm_hh  = (const float*)d_in[13];
  const float* bm_ih  = (const float*)d_in[14];
  const float* bm_hh  = (const float*)d_in[15];
  const float* Wd_ih  = (const float*)d_in[16];
  const float* Wd_hh  = (const float*)d_in[17];
  const float* bd_ih  = (const float*)d_in[18];
  const float* bd_hh  = (const float*)d_in[19];
  const float* W_dec  = (const float*)d_in[20];
  const float* b_dec  = (const float*)d_in[21];
  const float* W_p1   = (const float*)d_in[22];
  const float* b_p1   = (const float*)d_in[23];
  const float* W_p2   = (const float*)d_in[24];
  const float* b_p2   = (const float*)d_in[25];
  float* out = (float*)d_out;

  float* wsf   = (float*)d_ws;
  float* c_nt  = wsf;                 // B*N*T   = 524288
  float* c_btn = c_nt  + 524288;
  float* s1    = c_btn + 524288;
  float* s2    = s1    + 524288;
  float* h_cat = s2    + 524288;      // B*T*(H+N)
  float* gi    = h_cat + 1048576;     // B*T*3H
  float* h_enc = gi    + 1572864;
  float* h_dec = h_enc + 524288;
  float* ptmp  = h_dec + 524288;

  conv_selu_kernel<<<dim3(8, BB), 128, 0, stream>>>(x, conv_w, conv_b, c_nt, c_btn);
  linear_tiled<EE, TT, 16, 0><<<BB * NN / 16, EE, 0, stream>>>(c_nt, TT, Ww, 2 * TT, 0,  nullptr, s1, EE);
  linear_tiled<EE, TT, 16, 0><<<BB * NN / 16, EE, 0, stream>>>(c_nt, TT, Ww, 2 * TT, TT, nullptr, s2, EE);
  gat_kernel<<<dim3(NN, BB), 128, 0, stream>>>(s1, s2, bw, Wa, ba, c_nt, h_cat);
  linear_tiled<GG, NN, 16, 0><<<BB * TT / 16, GG, 0, stream>>>(c_btn, NN, We_ih, NN, 0, be_ih, gi, GG);
  gru_wave_kernel<<<BB, 64, 0, stream>>>(gi, We_hh, be_hh, h_cat, HH + NN);
  linear_tiled<GG, HH + NN, 16, 0><<<BB * TT / 16, GG, 0, stream>>>(h_cat, HH + NN, Wm_ih, HH + NN, 0, bm_ih, gi, GG);
  gru_wave_kernel<<<BB, 64, 0, stream>>>(gi, Wm_hh, bm_hh, h_enc, HH);
  linear_tiled<GG, HH, 16, 0><<<BB * TT / 16, GG, 0, stream>>>(h_enc, HH, Wd_ih, HH, 0, bd_ih, gi, GG);
  gru_wave_kernel<<<BB, 64, 0, stream>>>(gi, Wd_hh, bd_hh, h_dec, HH);
  linear_tiled<NN, HH, 16, 0><<<BB * TT / 16, NN, 0, stream>>>(h_dec, HH, W_dec, HH, 0, b_dec, out, NN);
  linear_tiled<NN, HH, 16, 1><<<BB / 16, NN, 0, stream>>>(h_dec, TT * HH, W_p1, HH, 0, b_p1, ptmp, NN);
  linear_tiled<NN, HH, 16, 0><<<BB / 16, NN, 0, stream>>>(ptmp, NN, W_p2, HH, 0, b_p2, out + BB * TT * NN, NN);
}

// Round 4
// 376.716 us; speedup vs baseline: 1.9827x; 1.0540x over previous
//
#include <hip/hip_runtime.h>
#include <math.h>

#define BB 64
#define TT 128
#define NN 64
#define HH 64
#define EE 128
#define KK 7
#define GG 192  // 3*H

__device__ __forceinline__ float sigmoidf_(float x){ return 1.f/(1.f+expf(-x)); }
__device__ __forceinline__ float fsig_(float x){ return __frcp_rn(1.f + __expf(-x)); }
__device__ __forceinline__ float ftanh_(float x){ return 2.f * __frcp_rn(1.f + __expf(-2.f * x)) - 1.f; }
__device__ __forceinline__ float bcast_(float v, int lane){
  return __uint_as_float(__builtin_amdgcn_readlane(__float_as_uint(v), lane));
}
__device__ __forceinline__ void loadrow_(float* d, const float* src){
  const float4* p = (const float4*)src;
  #pragma unroll
  for (int i = 0; i < 16; ++i) {
    float4 v = p[i];
    d[4*i] = v.x; d[4*i+1] = v.y; d[4*i+2] = v.z; d[4*i+3] = v.w;
  }
}
// 3-row matvec vs broadcast of hreg (all 64 lanes' values)
__device__ __forceinline__ void mv3_(float hreg, const float* w0, const float* w1, const float* w2,
                                     float& a0, float& a1, float& a2){
  #pragma unroll
  for (int k = 0; k < 64; ++k) {
    float hk = bcast_(hreg, k);
    a0 = fmaf(hk, w0[k], a0);
    a1 = fmaf(hk, w1[k], a1);
    a2 = fmaf(hk, w2[k], a2);
  }
}

// Conv1d (N->N, K=7, pad same) + SELU. 8 output channels per block.
__global__ void conv_selu_kernel(const float* __restrict__ x, const float* __restrict__ w,
                                 const float* __restrict__ bias,
                                 float* __restrict__ c_nt, float* __restrict__ c_btn) {
  const int og = blockIdx.x, b = blockIdx.y, t = threadIdx.x;
  const int o0 = og * 8;
  __shared__ __align__(16) float xs[NN][TT + 1];
  __shared__ __align__(16) float ws[NN * KK][8];
  for (int idx = t; idx < TT * NN; idx += 128) {
    int tt = idx >> 6, nn = idx & 63;
    xs[nn][tt] = x[(size_t)(b * TT + tt) * NN + nn];
  }
  for (int idx = t; idx < NN * KK * 8; idx += 128) {
    int oo = idx & 7, ik = idx >> 3;
    ws[ik][oo] = w[(size_t)(o0 + oo) * (NN * KK) + ik];
  }
  __syncthreads();
  float acc[8];
  #pragma unroll
  for (int oo = 0; oo < 8; ++oo) acc[oo] = bias[o0 + oo];
  for (int i = 0; i < NN; ++i) {
    #pragma unroll
    for (int k = 0; k < KK; ++k) {
      int tt = t + k - 3;
      if (tt >= 0 && tt < TT) {
        float xv = xs[i][tt];
        const float* wp = &ws[i * KK + k][0];
        float4 w0 = *(const float4*)wp;
        float4 w1 = *(const float4*)(wp + 4);
        acc[0] += xv * w0.x; acc[1] += xv * w0.y; acc[2] += xv * w0.z; acc[3] += xv * w0.w;
        acc[4] += xv * w1.x; acc[5] += xv * w1.y; acc[6] += xv * w1.z; acc[7] += xv * w1.w;
      }
    }
  }
  const float alpha = 1.6732632423543772f, scale = 1.0507009873554805f;
  #pragma unroll
  for (int oo = 0; oo < 8; ++oo) {
    float a = acc[oo];
    float r = a > 0.f ? scale * a : scale * alpha * expm1f(a);
    int o = o0 + oo;
    c_nt[((size_t)b * NN + o) * TT + t] = r;
    c_btn[((size_t)b * TT + t) * NN + o] = r;
  }
}

template<int NCOL, int KD, int TM, int ACT>
__global__ void linear_tiled(const float* __restrict__ in, int in_stride,
                             const float* __restrict__ W, int w_stride, int w_off,
                             const float* __restrict__ bias,
                             float* __restrict__ out, int out_stride) {
  const int m0 = blockIdx.x * TM, col = threadIdx.x;
  __shared__ __align__(16) float ins[TM][KD];
  for (int idx = col; idx < TM * KD; idx += NCOL) {
    int r = idx / KD, k = idx - r * KD;
    ins[r][k] = in[(size_t)(m0 + r) * in_stride + k];
  }
  __syncthreads();
  const float* wr = W + (size_t)col * w_stride + w_off;
  float bv = bias ? bias[col] : 0.f;
  float acc[TM];
  #pragma unroll
  for (int r = 0; r < TM; ++r) acc[r] = bv;
  #pragma unroll 2
  for (int k = 0; k < KD; k += 4) {
    float4 wv = *(const float4*)(wr + k);
    #pragma unroll
    for (int r = 0; r < TM; ++r) {
      float4 iv = *(const float4*)&ins[r][k];
      acc[r] += iv.x * wv.x + iv.y * wv.y + iv.z * wv.z + iv.w * wv.w;
    }
  }
  #pragma unroll
  for (int r = 0; r < TM; ++r) {
    float a = ACT ? fmaxf(acc[r], 0.f) : acc[r];
    out[(size_t)(m0 + r) * out_stride + col] = a;
  }
}

// GAT -> compact h_mp [B,T,N]
__global__ void gat_kernel(const float* __restrict__ s1, const float* __restrict__ s2,
                           const float* __restrict__ bw, const float* __restrict__ Wa,
                           const float* __restrict__ ba, const float* __restrict__ c_nt,
                           float* __restrict__ hmp) {
  const int i = blockIdx.x, b = blockIdx.y, tid = threadIdx.x;  // 128 threads
  __shared__ float s2s[NN][EE + 1];
  __shared__ float s1b[EE], was[EE], att[NN];
  for (int idx = tid; idx < NN * EE; idx += 128) {
    int r = idx >> 7, e = idx & 127;
    s2s[r][e] = s2[((size_t)b * NN + r) * EE + e];
  }
  s1b[tid] = s1[((size_t)b * NN + i) * EE + tid] + bw[tid];
  was[tid] = Wa[tid];
  __syncthreads();
  if (tid < NN) {
    float acc = 0.f;
    #pragma unroll 8
    for (int e = 0; e < EE; ++e) {
      float wv = s1b[e] + s2s[tid][e];
      wv = wv > 0.f ? wv : 0.2f * wv;
      acc += was[e] * wv;
    }
    float ej = acc + ba[0];
    float mx = ej;
    for (int off = 32; off >= 1; off >>= 1) mx = fmaxf(mx, __shfl_xor(mx, off));
    float ex = expf(ej - mx);
    float sm = ex;
    for (int off = 32; off >= 1; off >>= 1) sm += __shfl_xor(sm, off);
    att[tid] = ex / sm;
  }
  __syncthreads();
  float acc = 0.f;
  #pragma unroll 8
  for (int j = 0; j < NN; ++j) acc += att[j] * c_nt[((size_t)b * NN + j) * TT + tid];
  hmp[((size_t)b * TT + tid) * NN + i] = sigmoidf_(acc);
}

// Fused 3-GRU skewed pipeline. One block per batch, 3 waves (one per GRU stage).
// Wave w at phase ph handles timestep t = ph - w:
//   recurrence (register-held h, readlane broadcast) + gates, then projects new h
//   through the NEXT stage's W_ih and hands off via ping-pong LDS buffers.
// gi2's h_mp-dependent half is precomputed in pc2; gi3 bias added by consumer.
__global__ __launch_bounds__(192, 1)
void fused_chain_kernel(const float* __restrict__ gi1, const float* __restrict__ pc2,
                        const float* __restrict__ Wm_ih, const float* __restrict__ Wd_ih,
                        const float* __restrict__ We_hh, const float* __restrict__ Wm_hh,
                        const float* __restrict__ Wd_hh,
                        const float* __restrict__ be_hh, const float* __restrict__ bm_hh,
                        const float* __restrict__ bd_hh, const float* __restrict__ bd_ih,
                        float* __restrict__ h_dec) {
  const int b = blockIdx.x, tid = threadIdx.x, wv = tid >> 6, g = tid & 63;
  __shared__ float gi2buf[2][GG], gi3buf[2][GG];
  float wa[64], wb[64], wc[64];   // recurrence weight rows g, g+64, g+128
  float pa[64], pb[64], pc[64];   // projection weight rows (waves 0,1 only)

  const float* Wr = (wv == 0) ? We_hh : (wv == 1) ? Wm_hh : Wd_hh;
  loadrow_(wa, Wr + (size_t)g * HH);
  loadrow_(wb, Wr + (size_t)(g + 64) * HH);
  loadrow_(wc, Wr + (size_t)(g + 128) * HH);
  if (wv == 0) {            // Wm_ih [192][128], left half (cols 0..63)
    loadrow_(pa, Wm_ih + (size_t)g * 128);
    loadrow_(pb, Wm_ih + (size_t)(g + 64) * 128);
    loadrow_(pc, Wm_ih + (size_t)(g + 128) * 128);
  } else if (wv == 1) {     // Wd_ih [192][64]
    loadrow_(pa, Wd_ih + (size_t)g * HH);
    loadrow_(pb, Wd_ih + (size_t)(g + 64) * HH);
    loadrow_(pc, Wd_ih + (size_t)(g + 128) * HH);
  }
  const float* bh = (wv == 0) ? be_hh : (wv == 1) ? bm_hh : bd_hh;
  const float bh0 = bh[g], bh1 = bh[64 + g], bh2 = bh[128 + g];
  float bi0 = 0.f, bi1 = 0.f, bi2 = 0.f;
  if (wv == 2) { bi0 = bd_ih[g]; bi1 = bd_ih[64 + g]; bi2 = bd_ih[128 + g]; }

  float h = 0.f;
  const float* gi1p = gi1 + (size_t)b * TT * GG;
  const float* pc2p = pc2 + (size_t)b * TT * GG;

  for (int ph = 0; ph < TT + 2; ++ph) {
    if (wv == 0) {
      int t = ph;
      if (t < TT) {
        float gr = gi1p[t * GG + g], gz = gi1p[t * GG + 64 + g], gn = gi1p[t * GG + 128 + g];
        float a0 = bh0, a1 = bh1, a2 = bh2;
        mv3_(h, wa, wb, wc, a0, a1, a2);
        float r = fsig_(gr + a0), z = fsig_(gz + a1), n = ftanh_(gn + r * a2);
        h = fmaf(z, h - n, n);
        float q0 = 0.f, q1 = 0.f, q2 = 0.f;
        mv3_(h, pa, pb, pc, q0, q1, q2);
        gi2buf[ph & 1][g] = q0; gi2buf[ph & 1][64 + g] = q1; gi2buf[ph & 1][128 + g] = q2;
      }
    } else if (wv == 1) {
      int t = ph - 1;
      if (t >= 0 && t < TT) {
        int s = (ph - 1) & 1;
        float gr = gi2buf[s][g]       + pc2p[t * GG + g];
        float gz = gi2buf[s][64 + g]  + pc2p[t * GG + 64 + g];
        float gn = gi2buf[s][128 + g] + pc2p[t * GG + 128 + g];
        float a0 = bh0, a1 = bh1, a2 = bh2;
        mv3_(h, wa, wb, wc, a0, a1, a2);
        float r = fsig_(gr + a0), z = fsig_(gz + a1), n = ftanh_(gn + r * a2);
        h = fmaf(z, h - n, n);
        float q0 = 0.f, q1 = 0.f, q2 = 0.f;
        mv3_(h, pa, pb, pc, q0, q1, q2);
        gi3buf[ph & 1][g] = q0; gi3buf[ph & 1][64 + g] = q1; gi3buf[ph & 1][128 + g] = q2;
      }
    } else {
      int t = ph - 2;
      if (t >= 0) {
        int s = (ph - 1) & 1;
        float gr = gi3buf[s][g] + bi0, gz = gi3buf[s][64 + g] + bi1, gn = gi3buf[s][128 + g] + bi2;
        float a0 = bh0, a1 = bh1, a2 = bh2;
        mv3_(h, wa, wb, wc, a0, a1, a2);
        float r = fsig_(gr + a0), z = fsig_(gz + a1), n = ftanh_(gn + r * a2);
        h = fmaf(z, h - n, n);
        h_dec[((size_t)b * TT + t) * HH + g] = h;
      }
    }
    __syncthreads();
  }
}

extern "C" void kernel_launch(void* const* d_in, const int* in_sizes, int n_in,
                              void* d_out, int out_size, void* d_ws, size_t ws_size,
                              hipStream_t stream) {
  const float* x      = (const float*)d_in[0];
  const float* conv_w = (const float*)d_in[2];
  const float* conv_b = (const float*)d_in[3];
  const float* We_ih  = (const float*)d_in[4];
  const float* We_hh  = (const float*)d_in[5];
  const float* be_ih  = (const float*)d_in[6];
  const float* be_hh  = (const float*)d_in[7];
  const float* Ww     = (const float*)d_in[8];
  const float* bw     = (const float*)d_in[9];
  const float* Wa     = (const float*)d_in[10];
  const float* ba     = (const float*)d_in[11];
  const float* Wm_ih  = (const float*)d_in[12];
  const float* Wm_hh  = (const float*)d_in[13];
  const float* bm_ih  = (const float*)d_in[14];
  const float* bm_hh  = (const float*)d_in[15];
  const float* Wd_ih  = (const float*)d_in[16];
  const float* Wd_hh  = (const float*)d_in[17];
  const float* bd_ih  = (const float*)d_in[18];
  const float* bd_hh  = (const float*)d_in[19];
  const float* W_dec  = (const float*)d_in[20];
  const float* b_dec  = (const float*)d_in[21];
  const float* W_p1   = (const float*)d_in[22];
  const float* b_p1   = (const float*)d_in[23];
  const float* W_p2   = (const float*)d_in[24];
  const float* b_p2   = (const float*)d_in[25];
  float* out = (float*)d_out;

  float* wsf   = (float*)d_ws;
  float* c_nt  = wsf;                 // B*N*T    = 524288
  float* c_btn = c_nt  + 524288;      // B*T*N    = 524288
  float* s1    = c_btn + 524288;      // B*N*E    = 524288
  float* s2    = s1    + 524288;      // B*N*E    = 524288
  float* hmp   = s2    + 524288;      // B*T*N    = 524288
  float* pc2   = hmp   + 524288;      // B*T*3H   = 1572864
  float* gi1   = pc2   + 1572864;     // B*T*3H   = 1572864
  float* h_dec = gi1   + 1572864;     // B*T*H    = 524288
  float* ptmp  = h_dec + 524288;      // B*N      = 4096

  conv_selu_kernel<<<dim3(8, BB), 128, 0, stream>>>(x, conv_w, conv_b, c_nt, c_btn);
  linear_tiled<EE, TT, 16, 0><<<BB * NN / 16, EE, 0, stream>>>(c_nt, TT, Ww, 2 * TT, 0,  nullptr, s1, EE);
  linear_tiled<EE, TT, 16, 0><<<BB * NN / 16, EE, 0, stream>>>(c_nt, TT, Ww, 2 * TT, TT, nullptr, s2, EE);
  gat_kernel<<<dim3(NN, BB), 128, 0, stream>>>(s1, s2, bw, Wa, ba, c_nt, hmp);
  // bulk projections (parallel over B*T rows)
  linear_tiled<GG, NN, 16, 0><<<BB * TT / 16, GG, 0, stream>>>(c_btn, NN, We_ih, NN, 0, be_ih, gi1, GG);
  linear_tiled<GG, NN, 16, 0><<<BB * TT / 16, GG, 0, stream>>>(hmp, NN, Wm_ih, 2 * NN, NN, bm_ih, pc2, GG);
  // fused 3-stage GRU pipeline
  fused_chain_kernel<<<BB, 192, 0, stream>>>(gi1, pc2, Wm_ih, Wd_ih, We_hh, Wm_hh, Wd_hh,
                                             be_hh, bm_hh, bd_hh, bd_ih, h_dec);
  // heads
  linear_tiled<NN, HH, 16, 0><<<BB * TT / 16, NN, 0, stream>>>(h_dec, HH, W_dec, HH, 0, b_dec, out, NN);
  linear_tiled<NN, HH, 16, 1><<<BB / 16, NN, 0, stream>>>(h_dec, TT * HH, W_p1, HH, 0, b_p1, ptmp, NN);
  linear_tiled<NN, HH, 16, 0><<<BB / 16, NN, 0, stream>>>(ptmp, NN, W_p2, HH, 0, b_p2, out + BB * TT * NN, NN);
}

// Round 5
// 300.545 us; speedup vs baseline: 2.4852x; 1.2534x over previous
//
#include <hip/hip_runtime.h>
#include <math.h>

#define BB 64
#define TT 128
#define NN 64
#define HH 64
#define EE 128
#define KK 7
#define GG 192  // 3*H

__device__ __forceinline__ float sigmoidf_(float x){ return 1.f/(1.f+expf(-x)); }
__device__ __forceinline__ float fsig_(float x){ return __frcp_rn(1.f + __expf(-x)); }
__device__ __forceinline__ float ftanh_(float x){ return 2.f * __frcp_rn(1.f + __expf(-2.f * x)) - 1.f; }

__device__ __forceinline__ void loadrow_(float* d, const float* src){
  const float4* p = (const float4*)src;
  #pragma unroll
  for (int i = 0; i < 16; ++i) {
    float4 v = p[i];
    d[4*i] = v.x; d[4*i+1] = v.y; d[4*i+2] = v.z; d[4*i+3] = v.w;
  }
}
// 3-row matvec; h comes from LDS via same-address b128 broadcast reads.
__device__ __forceinline__ void mv3lds_(const float* hs, const float* w0, const float* w1,
                                        const float* w2, float& a0, float& a1, float& a2){
  const float4* h4 = (const float4*)hs;
  #pragma unroll
  for (int i = 0; i < 16; ++i) {
    float4 hv = h4[i];
    a0 = fmaf(hv.x, w0[4*i], fmaf(hv.y, w0[4*i+1], fmaf(hv.z, w0[4*i+2], fmaf(hv.w, w0[4*i+3], a0))));
    a1 = fmaf(hv.x, w1[4*i], fmaf(hv.y, w1[4*i+1], fmaf(hv.z, w1[4*i+2], fmaf(hv.w, w1[4*i+3], a1))));
    a2 = fmaf(hv.x, w2[4*i], fmaf(hv.y, w2[4*i+1], fmaf(hv.z, w2[4*i+2], fmaf(hv.w, w2[4*i+3], a2))));
  }
}

// Conv1d (N->N, K=7, pad same) + SELU. 8 output channels per block.
__global__ void conv_selu_kernel(const float* __restrict__ x, const float* __restrict__ w,
                                 const float* __restrict__ bias,
                                 float* __restrict__ c_nt, float* __restrict__ c_btn) {
  const int og = blockIdx.x, b = blockIdx.y, t = threadIdx.x;
  const int o0 = og * 8;
  __shared__ __align__(16) float xs[NN][TT + 1];
  __shared__ __align__(16) float ws[NN * KK][8];
  for (int idx = t; idx < TT * NN; idx += 128) {
    int tt = idx >> 6, nn = idx & 63;
    xs[nn][tt] = x[(size_t)(b * TT + tt) * NN + nn];
  }
  for (int idx = t; idx < NN * KK * 8; idx += 128) {
    int oo = idx & 7, ik = idx >> 3;
    ws[ik][oo] = w[(size_t)(o0 + oo) * (NN * KK) + ik];
  }
  __syncthreads();
  float acc[8];
  #pragma unroll
  for (int oo = 0; oo < 8; ++oo) acc[oo] = bias[o0 + oo];
  for (int i = 0; i < NN; ++i) {
    #pragma unroll
    for (int k = 0; k < KK; ++k) {
      int tt = t + k - 3;
      if (tt >= 0 && tt < TT) {
        float xv = xs[i][tt];
        const float* wp = &ws[i * KK + k][0];
        float4 w0 = *(const float4*)wp;
        float4 w1 = *(const float4*)(wp + 4);
        acc[0] += xv * w0.x; acc[1] += xv * w0.y; acc[2] += xv * w0.z; acc[3] += xv * w0.w;
        acc[4] += xv * w1.x; acc[5] += xv * w1.y; acc[6] += xv * w1.z; acc[7] += xv * w1.w;
      }
    }
  }
  const float alpha = 1.6732632423543772f, scale = 1.0507009873554805f;
  #pragma unroll
  for (int oo = 0; oo < 8; ++oo) {
    float a = acc[oo];
    float r = a > 0.f ? scale * a : scale * alpha * expm1f(a);
    int o = o0 + oo;
    c_nt[((size_t)b * NN + o) * TT + t] = r;
    c_btn[((size_t)b * TT + t) * NN + o] = r;
  }
}

template<int NCOL, int KD, int TM, int ACT>
__global__ void linear_tiled(const float* __restrict__ in, int in_stride,
                             const float* __restrict__ W, int w_stride, int w_off,
                             const float* __restrict__ bias,
                             float* __restrict__ out, int out_stride) {
  const int m0 = blockIdx.x * TM, col = threadIdx.x;
  __shared__ __align__(16) float ins[TM][KD];
  for (int idx = col; idx < TM * KD; idx += NCOL) {
    int r = idx / KD, k = idx - r * KD;
    ins[r][k] = in[(size_t)(m0 + r) * in_stride + k];
  }
  __syncthreads();
  const float* wr = W + (size_t)col * w_stride + w_off;
  float bv = bias ? bias[col] : 0.f;
  float acc[TM];
  #pragma unroll
  for (int r = 0; r < TM; ++r) acc[r] = bv;
  #pragma unroll 2
  for (int k = 0; k < KD; k += 4) {
    float4 wv = *(const float4*)(wr + k);
    #pragma unroll
    for (int r = 0; r < TM; ++r) {
      float4 iv = *(const float4*)&ins[r][k];
      acc[r] += iv.x * wv.x + iv.y * wv.y + iv.z * wv.z + iv.w * wv.w;
    }
  }
  #pragma unroll
  for (int r = 0; r < TM; ++r) {
    float a = ACT ? fmaxf(acc[r], 0.f) : acc[r];
    out[(size_t)(m0 + r) * out_stride + col] = a;
  }
}

// Fused s1 + s2 projection: one pass over c_nt rows, both halves of Ww.
__global__ void s12_kernel(const float* __restrict__ c_nt, const float* __restrict__ Ww,
                           float* __restrict__ s1, float* __restrict__ s2) {
  const int m0 = blockIdx.x * 16, col = threadIdx.x;  // 128 threads
  __shared__ __align__(16) float ins[16][TT];
  for (int idx = col; idx < 16 * TT; idx += 128) {
    int r = idx >> 7, k = idx & 127;
    ins[r][k] = c_nt[(size_t)(m0 + r) * TT + k];
  }
  __syncthreads();
  const float* w1 = Ww + (size_t)col * (2 * TT);
  const float* w2 = w1 + TT;
  float acc1[16], acc2[16];
  #pragma unroll
  for (int r = 0; r < 16; ++r) { acc1[r] = 0.f; acc2[r] = 0.f; }
  #pragma unroll 2
  for (int k = 0; k < TT; k += 4) {
    float4 wv1 = *(const float4*)(w1 + k);
    float4 wv2 = *(const float4*)(w2 + k);
    #pragma unroll
    for (int r = 0; r < 16; ++r) {
      float4 iv = *(const float4*)&ins[r][k];
      acc1[r] += iv.x * wv1.x + iv.y * wv1.y + iv.z * wv1.z + iv.w * wv1.w;
      acc2[r] += iv.x * wv2.x + iv.y * wv2.y + iv.z * wv2.z + iv.w * wv2.w;
    }
  }
  #pragma unroll
  for (int r = 0; r < 16; ++r) {
    s1[(size_t)(m0 + r) * EE + col] = acc1[r];
    s2[(size_t)(m0 + r) * EE + col] = acc2[r];
  }
}

// GAT -> compact h_mp [B,T,N]
__global__ void gat_kernel(const float* __restrict__ s1, const float* __restrict__ s2,
                           const float* __restrict__ bw, const float* __restrict__ Wa,
                           const float* __restrict__ ba, const float* __restrict__ c_nt,
                           float* __restrict__ hmp) {
  const int i = blockIdx.x, b = blockIdx.y, tid = threadIdx.x;  // 128 threads
  __shared__ float s2s[NN][EE + 1];
  __shared__ float s1b[EE], was[EE], att[NN];
  for (int idx = tid; idx < NN * EE; idx += 128) {
    int r = idx >> 7, e = idx & 127;
    s2s[r][e] = s2[((size_t)b * NN + r) * EE + e];
  }
  s1b[tid] = s1[((size_t)b * NN + i) * EE + tid] + bw[tid];
  was[tid] = Wa[tid];
  __syncthreads();
  if (tid < NN) {
    float acc = 0.f;
    #pragma unroll 8
    for (int e = 0; e < EE; ++e) {
      float wv = s1b[e] + s2s[tid][e];
      wv = wv > 0.f ? wv : 0.2f * wv;
      acc += was[e] * wv;
    }
    float ej = acc + ba[0];
    float mx = ej;
    for (int off = 32; off >= 1; off >>= 1) mx = fmaxf(mx, __shfl_xor(mx, off));
    float ex = expf(ej - mx);
    float sm = ex;
    for (int off = 32; off >= 1; off >>= 1) sm += __shfl_xor(sm, off);
    att[tid] = ex / sm;
  }
  __syncthreads();
  float acc = 0.f;
  #pragma unroll 8
  for (int j = 0; j < NN; ++j) acc += att[j] * c_nt[((size_t)b * NN + j) * TT + tid];
  hmp[((size_t)b * TT + tid) * NN + i] = sigmoidf_(acc);
}

// Fused 3-GRU, 5-deep skewed pipeline. One block per batch, 5 waves, ONE matvec per
// wave per phase: w0=rec1, w1=proj1->2, w2=rec2, w3=proj2->3, w4=rec3.
// Handoffs via double-buffered LDS; h broadcast via same-address ds_read_b128
// (no readlane). 192 weight floats per lane -> VGPR-resident.
__global__ __launch_bounds__(320, 1)
void fused_chain5(const float* __restrict__ gi1, const float* __restrict__ pc2,
                  const float* __restrict__ Wm_ih, const float* __restrict__ Wd_ih,
                  const float* __restrict__ We_hh, const float* __restrict__ Wm_hh,
                  const float* __restrict__ Wd_hh,
                  const float* __restrict__ be_hh, const float* __restrict__ bm_hh,
                  const float* __restrict__ bd_hh, const float* __restrict__ bd_ih,
                  float* __restrict__ h_dec) {
  const int b = blockIdx.x, tid = threadIdx.x, wv = tid >> 6, g = tid & 63;
  __shared__ __align__(16) float h1[2][HH], h2[2][HH], h3[2][HH];
  __shared__ __align__(16) float q2[2][GG], q3[2][GG];

  float wa[64], wb[64], wc[64];
  if (wv == 0) {
    loadrow_(wa, We_hh + (size_t)g * HH);
    loadrow_(wb, We_hh + (size_t)(g + 64) * HH);
    loadrow_(wc, We_hh + (size_t)(g + 128) * HH);
  } else if (wv == 1) {      // Wm_ih [192][128], cols 0..63
    loadrow_(wa, Wm_ih + (size_t)g * 128);
    loadrow_(wb, Wm_ih + (size_t)(g + 64) * 128);
    loadrow_(wc, Wm_ih + (size_t)(g + 128) * 128);
  } else if (wv == 2) {
    loadrow_(wa, Wm_hh + (size_t)g * HH);
    loadrow_(wb, Wm_hh + (size_t)(g + 64) * HH);
    loadrow_(wc, Wm_hh + (size_t)(g + 128) * HH);
  } else if (wv == 3) {      // Wd_ih [192][64]
    loadrow_(wa, Wd_ih + (size_t)g * HH);
    loadrow_(wb, Wd_ih + (size_t)(g + 64) * HH);
    loadrow_(wc, Wd_ih + (size_t)(g + 128) * HH);
  } else {
    loadrow_(wa, Wd_hh + (size_t)g * HH);
    loadrow_(wb, Wd_hh + (size_t)(g + 64) * HH);
    loadrow_(wc, Wd_hh + (size_t)(g + 128) * HH);
  }
  float bh0 = 0.f, bh1 = 0.f, bh2 = 0.f;
  if (wv == 0) { bh0 = be_hh[g]; bh1 = be_hh[64 + g]; bh2 = be_hh[128 + g]; }
  if (wv == 2) { bh0 = bm_hh[g]; bh1 = bm_hh[64 + g]; bh2 = bm_hh[128 + g]; }
  if (wv == 4) { bh0 = bd_hh[g]; bh1 = bd_hh[64 + g]; bh2 = bd_hh[128 + g]; }
  float bi0 = 0.f, bi1 = 0.f, bi2 = 0.f;
  if (wv == 4) { bi0 = bd_ih[g]; bi1 = bd_ih[64 + g]; bi2 = bd_ih[128 + g]; }

  if (wv == 0) { h1[1][g] = 0.f; h2[1][g] = 0.f; h3[1][g] = 0.f; }
  __syncthreads();

  const float* gi1p = gi1 + (size_t)b * TT * GG;
  const float* pc2p = pc2 + (size_t)b * TT * GG;
  float hown = 0.f;  // rec waves: own h (same value as LDS copy, avoids re-read)

  for (int ph = 0; ph < TT + 4; ++ph) {
    const int pw = ph & 1, pr = (ph - 1) & 1;
    if (wv == 0) {
      int t = ph;
      if (t < TT) {
        float gr = gi1p[t * GG + g], gz = gi1p[t * GG + 64 + g], gn = gi1p[t * GG + 128 + g];
        float a0 = bh0, a1 = bh1, a2 = bh2;
        mv3lds_(&h1[pr][0], wa, wb, wc, a0, a1, a2);
        float r = fsig_(gr + a0), z = fsig_(gz + a1), n = ftanh_(gn + r * a2);
        hown = fmaf(z, hown - n, n);
        h1[pw][g] = hown;
      }
    } else if (wv == 1) {
      if (ph >= 1 && ph <= TT) {
        float a0 = 0.f, a1 = 0.f, a2 = 0.f;
        mv3lds_(&h1[pr][0], wa, wb, wc, a0, a1, a2);
        q2[pw][g] = a0; q2[pw][64 + g] = a1; q2[pw][128 + g] = a2;
      }
    } else if (wv == 2) {
      int t = ph - 2;
      if (t >= 0 && t < TT) {
        float gr = q2[pr][g]       + pc2p[t * GG + g];
        float gz = q2[pr][64 + g]  + pc2p[t * GG + 64 + g];
        float gn = q2[pr][128 + g] + pc2p[t * GG + 128 + g];
        float a0 = bh0, a1 = bh1, a2 = bh2;
        mv3lds_(&h2[pr][0], wa, wb, wc, a0, a1, a2);
        float r = fsig_(gr + a0), z = fsig_(gz + a1), n = ftanh_(gn + r * a2);
        hown = fmaf(z, hown - n, n);
        h2[pw][g] = hown;
      }
    } else if (wv == 3) {
      if (ph >= 3 && ph <= TT + 2) {
        float a0 = 0.f, a1 = 0.f, a2 = 0.f;
        mv3lds_(&h2[pr][0], wa, wb, wc, a0, a1, a2);
        q3[pw][g] = a0; q3[pw][64 + g] = a1; q3[pw][128 + g] = a2;
      }
    } else {
      int t = ph - 4;
      if (t >= 0) {
        float gr = q3[pr][g] + bi0, gz = q3[pr][64 + g] + bi1, gn = q3[pr][128 + g] + bi2;
        float a0 = bh0, a1 = bh1, a2 = bh2;
        mv3lds_(&h3[pr][0], wa, wb, wc, a0, a1, a2);
        float r = fsig_(gr + a0), z = fsig_(gz + a1), n = ftanh_(gn + r * a2);
        hown = fmaf(z, hown - n, n);
        h3[pw][g] = hown;
        h_dec[((size_t)b * TT + t) * HH + g] = hown;
      }
    }
    __syncthreads();
  }
}

extern "C" void kernel_launch(void* const* d_in, const int* in_sizes, int n_in,
                              void* d_out, int out_size, void* d_ws, size_t ws_size,
                              hipStream_t stream) {
  const float* x      = (const float*)d_in[0];
  const float* conv_w = (const float*)d_in[2];
  const float* conv_b = (const float*)d_in[3];
  const float* We_ih  = (const float*)d_in[4];
  const float* We_hh  = (const float*)d_in[5];
  const float* be_ih  = (const float*)d_in[6];
  const float* be_hh  = (const float*)d_in[7];
  const float* Ww     = (const float*)d_in[8];
  const float* bw     = (const float*)d_in[9];
  const float* Wa     = (const float*)d_in[10];
  const float* ba     = (const float*)d_in[11];
  const float* Wm_ih  = (const float*)d_in[12];
  const float* Wm_hh  = (const float*)d_in[13];
  const float* bm_ih  = (const float*)d_in[14];
  const float* bm_hh  = (const float*)d_in[15];
  const float* Wd_ih  = (const float*)d_in[16];
  const float* Wd_hh  = (const float*)d_in[17];
  const float* bd_ih  = (const float*)d_in[18];
  const float* bd_hh  = (const float*)d_in[19];
  const float* W_dec  = (const float*)d_in[20];
  const float* b_dec  = (const float*)d_in[21];
  const float* W_p1   = (const float*)d_in[22];
  const float* b_p1   = (const float*)d_in[23];
  const float* W_p2   = (const float*)d_in[24];
  const float* b_p2   = (const float*)d_in[25];
  float* out = (float*)d_out;

  float* wsf   = (float*)d_ws;
  float* c_nt  = wsf;                 // B*N*T    = 524288
  float* c_btn = c_nt  + 524288;      // B*T*N    = 524288
  float* s1    = c_btn + 524288;      // B*N*E    = 524288
  float* s2    = s1    + 524288;      // B*N*E    = 524288
  float* hmp   = s2    + 524288;      // B*T*N    = 524288
  float* pc2   = hmp   + 524288;      // B*T*3H   = 1572864
  float* gi1   = pc2   + 1572864;     // B*T*3H   = 1572864
  float* h_dec = gi1   + 1572864;     // B*T*H    = 524288
  float* ptmp  = h_dec + 524288;      // B*N      = 4096

  conv_selu_kernel<<<dim3(8, BB), 128, 0, stream>>>(x, conv_w, conv_b, c_nt, c_btn);
  s12_kernel<<<BB * NN / 16, 128, 0, stream>>>(c_nt, Ww, s1, s2);
  gat_kernel<<<dim3(NN, BB), 128, 0, stream>>>(s1, s2, bw, Wa, ba, c_nt, hmp);
  // bulk projections (parallel over B*T rows)
  linear_tiled<GG, NN, 16, 0><<<BB * TT / 16, GG, 0, stream>>>(c_btn, NN, We_ih, NN, 0, be_ih, gi1, GG);
  linear_tiled<GG, NN, 16, 0><<<BB * TT / 16, GG, 0, stream>>>(hmp, NN, Wm_ih, 2 * NN, NN, bm_ih, pc2, GG);
  // fused 3-GRU, 5-wave skewed pipeline
  fused_chain5<<<BB, 320, 0, stream>>>(gi1, pc2, Wm_ih, Wd_ih, We_hh, Wm_hh, Wd_hh,
                                       be_hh, bm_hh, bd_hh, bd_ih, h_dec);
  // heads
  linear_tiled<NN, HH, 16, 0><<<BB * TT / 16, NN, 0, stream>>>(h_dec, HH, W_dec, HH, 0, b_dec, out, NN);
  linear_tiled<NN, HH, 16, 1><<<BB / 16, NN, 0, stream>>>(h_dec, TT * HH, W_p1, HH, 0, b_p1, ptmp, NN);
  linear_tiled<NN, HH, 16, 0><<<BB / 16, NN, 0, stream>>>(ptmp, NN, W_p2, HH, 0, b_p2, out + BB * TT * NN, NN);
}

// Round 6
// 239.348 us; speedup vs baseline: 3.1206x; 1.2557x over previous
//
#include <hip/hip_runtime.h>
#include <math.h>

#define BB 64
#define TT 128
#define NN 64
#define HH 64
#define EE 128
#define KK 7
#define GG 192  // 3*H

typedef _Float16 half2_t __attribute__((ext_vector_type(2)));

__device__ __forceinline__ float sigmoidf_(float x){ return 1.f/(1.f+expf(-x)); }
__device__ __forceinline__ float fsig_(float x){ return __frcp_rn(1.f + __expf(-x)); }
__device__ __forceinline__ float ftanh_(float x){ return 2.f * __frcp_rn(1.f + __expf(-2.f * x)) - 1.f; }

__device__ __forceinline__ void loadrow_(float* d, const float* src){
  const float4* p = (const float4*)src;
  #pragma unroll
  for (int i = 0; i < 16; ++i) {
    float4 v = p[i];
    d[4*i] = v.x; d[4*i+1] = v.y; d[4*i+2] = v.z; d[4*i+3] = v.w;
  }
}
// load 64 fp32 weights -> 32 packed f16 pairs (RNE converts)
__device__ __forceinline__ void loadroww_(half2_t* d, const float* src){
  const float4* p = (const float4*)src;
  #pragma unroll
  for (int i = 0; i < 16; ++i) {
    float4 v = p[i];
    d[2*i]   = half2_t{(_Float16)v.x, (_Float16)v.y};
    d[2*i+1] = half2_t{(_Float16)v.z, (_Float16)v.w};
  }
}
// read 64 f16 values (128B) from LDS as 32 packed pairs via b128 chunks
__device__ __forceinline__ void load_h16_(const _Float16* hs, half2_t* hp){
  const float4* s4 = (const float4*)hs;
  #pragma unroll
  for (int j = 0; j < 8; ++j) {
    float4 v = s4[j];
    const half2_t* q = (const half2_t*)&v;
    hp[4*j] = q[0]; hp[4*j+1] = q[1]; hp[4*j+2] = q[2]; hp[4*j+3] = q[3];
  }
}
// 3-row matvec via v_dot2_f32_f16 (fp32 accumulate)
__device__ __forceinline__ void mvdot3_(const half2_t* hp, const half2_t* w0,
                                        const half2_t* w1, const half2_t* w2,
                                        float& a0, float& a1, float& a2){
  #pragma unroll
  for (int i = 0; i < 32; ++i) {
    a0 = __builtin_amdgcn_fdot2(hp[i], w0[i], a0, false);
    a1 = __builtin_amdgcn_fdot2(hp[i], w1[i], a1, false);
    a2 = __builtin_amdgcn_fdot2(hp[i], w2[i], a2, false);
  }
}

// Conv1d (N->N, K=7, pad same) + SELU. 8 output channels per block.
__global__ void conv_selu_kernel(const float* __restrict__ x, const float* __restrict__ w,
                                 const float* __restrict__ bias,
                                 float* __restrict__ c_nt, float* __restrict__ c_btn) {
  const int og = blockIdx.x, b = blockIdx.y, t = threadIdx.x;
  const int o0 = og * 8;
  __shared__ __align__(16) float xs[NN][TT + 1];
  __shared__ __align__(16) float ws[NN * KK][8];
  for (int idx = t; idx < TT * NN; idx += 128) {
    int tt = idx >> 6, nn = idx & 63;
    xs[nn][tt] = x[(size_t)(b * TT + tt) * NN + nn];
  }
  for (int idx = t; idx < NN * KK * 8; idx += 128) {
    int oo = idx & 7, ik = idx >> 3;
    ws[ik][oo] = w[(size_t)(o0 + oo) * (NN * KK) + ik];
  }
  __syncthreads();
  float acc[8];
  #pragma unroll
  for (int oo = 0; oo < 8; ++oo) acc[oo] = bias[o0 + oo];
  for (int i = 0; i < NN; ++i) {
    #pragma unroll
    for (int k = 0; k < KK; ++k) {
      int tt = t + k - 3;
      if (tt >= 0 && tt < TT) {
        float xv = xs[i][tt];
        const float* wp = &ws[i * KK + k][0];
        float4 w0 = *(const float4*)wp;
        float4 w1 = *(const float4*)(wp + 4);
        acc[0] += xv * w0.x; acc[1] += xv * w0.y; acc[2] += xv * w0.z; acc[3] += xv * w0.w;
        acc[4] += xv * w1.x; acc[5] += xv * w1.y; acc[6] += xv * w1.z; acc[7] += xv * w1.w;
      }
    }
  }
  const float alpha = 1.6732632423543772f, scale = 1.0507009873554805f;
  #pragma unroll
  for (int oo = 0; oo < 8; ++oo) {
    float a = acc[oo];
    float r = a > 0.f ? scale * a : scale * alpha * expm1f(a);
    int o = o0 + oo;
    c_nt[((size_t)b * NN + o) * TT + t] = r;
    c_btn[((size_t)b * TT + t) * NN + o] = r;
  }
}

template<int NCOL, int KD, int TM, int ACT>
__global__ void linear_tiled(const float* __restrict__ in, int in_stride,
                             const float* __restrict__ W, int w_stride, int w_off,
                             const float* __restrict__ bias,
                             float* __restrict__ out, int out_stride) {
  const int m0 = blockIdx.x * TM, col = threadIdx.x;
  __shared__ __align__(16) float ins[TM][KD];
  for (int idx = col; idx < TM * KD; idx += NCOL) {
    int r = idx / KD, k = idx - r * KD;
    ins[r][k] = in[(size_t)(m0 + r) * in_stride + k];
  }
  __syncthreads();
  const float* wr = W + (size_t)col * w_stride + w_off;
  float bv = bias ? bias[col] : 0.f;
  float acc[TM];
  #pragma unroll
  for (int r = 0; r < TM; ++r) acc[r] = bv;
  #pragma unroll 2
  for (int k = 0; k < KD; k += 4) {
    float4 wv = *(const float4*)(wr + k);
    #pragma unroll
    for (int r = 0; r < TM; ++r) {
      float4 iv = *(const float4*)&ins[r][k];
      acc[r] += iv.x * wv.x + iv.y * wv.y + iv.z * wv.z + iv.w * wv.w;
    }
  }
  #pragma unroll
  for (int r = 0; r < TM; ++r) {
    float a = ACT ? fmaxf(acc[r], 0.f) : acc[r];
    out[(size_t)(m0 + r) * out_stride + col] = a;
  }
}

// Fused s1 + s2 projection
__global__ void s12_kernel(const float* __restrict__ c_nt, const float* __restrict__ Ww,
                           float* __restrict__ s1, float* __restrict__ s2) {
  const int m0 = blockIdx.x * 16, col = threadIdx.x;  // 128 threads
  __shared__ __align__(16) float ins[16][TT];
  for (int idx = col; idx < 16 * TT; idx += 128) {
    int r = idx >> 7, k = idx & 127;
    ins[r][k] = c_nt[(size_t)(m0 + r) * TT + k];
  }
  __syncthreads();
  const float* w1 = Ww + (size_t)col * (2 * TT);
  const float* w2 = w1 + TT;
  float acc1[16], acc2[16];
  #pragma unroll
  for (int r = 0; r < 16; ++r) { acc1[r] = 0.f; acc2[r] = 0.f; }
  #pragma unroll 2
  for (int k = 0; k < TT; k += 4) {
    float4 wv1 = *(const float4*)(w1 + k);
    float4 wv2 = *(const float4*)(w2 + k);
    #pragma unroll
    for (int r = 0; r < 16; ++r) {
      float4 iv = *(const float4*)&ins[r][k];
      acc1[r] += iv.x * wv1.x + iv.y * wv1.y + iv.z * wv1.z + iv.w * wv1.w;
      acc2[r] += iv.x * wv2.x + iv.y * wv2.y + iv.z * wv2.z + iv.w * wv2.w;
    }
  }
  #pragma unroll
  for (int r = 0; r < 16; ++r) {
    s1[(size_t)(m0 + r) * EE + col] = acc1[r];
    s2[(size_t)(m0 + r) * EE + col] = acc2[r];
  }
}

// GAT -> compact h_mp [B,T,N]
__global__ void gat_kernel(const float* __restrict__ s1, const float* __restrict__ s2,
                           const float* __restrict__ bw, const float* __restrict__ Wa,
                           const float* __restrict__ ba, const float* __restrict__ c_nt,
                           float* __restrict__ hmp) {
  const int i = blockIdx.x, b = blockIdx.y, tid = threadIdx.x;  // 128 threads
  __shared__ float s2s[NN][EE + 1];
  __shared__ float s1b[EE], was[EE], att[NN];
  for (int idx = tid; idx < NN * EE; idx += 128) {
    int r = idx >> 7, e = idx & 127;
    s2s[r][e] = s2[((size_t)b * NN + r) * EE + e];
  }
  s1b[tid] = s1[((size_t)b * NN + i) * EE + tid] + bw[tid];
  was[tid] = Wa[tid];
  __syncthreads();
  if (tid < NN) {
    float acc = 0.f;
    #pragma unroll 8
    for (int e = 0; e < EE; ++e) {
      float wv = s1b[e] + s2s[tid][e];
      wv = wv > 0.f ? wv : 0.2f * wv;
      acc += was[e] * wv;
    }
    float ej = acc + ba[0];
    float mx = ej;
    for (int off = 32; off >= 1; off >>= 1) mx = fmaxf(mx, __shfl_xor(mx, off));
    float ex = expf(ej - mx);
    float sm = ex;
    for (int off = 32; off >= 1; off >>= 1) sm += __shfl_xor(sm, off);
    att[tid] = ex / sm;
  }
  __syncthreads();
  float acc = 0.f;
  #pragma unroll 8
  for (int j = 0; j < NN; ++j) acc += att[j] * c_nt[((size_t)b * NN + j) * TT + tid];
  hmp[((size_t)b * TT + tid) * NN + i] = sigmoidf_(acc);
}

// Fused 3-GRU + recon head, 6-wave skewed pipeline (one block per batch).
// Roles: w0=rec1, w1=proj1->2, w2=rec2, w3=proj2->3, w4=rec3, w5=recon.
// Matvecs use packed-f16 weights + v_dot2_f32_f16 (fp32 accumulate); recurrence
// state h stays fp32. Global gi/pc2 prefetched one phase ahead.
__global__ __launch_bounds__(384, 1)
void fused_chain6(const float* __restrict__ gi1, const float* __restrict__ pc2,
                  const float* __restrict__ Wm_ih, const float* __restrict__ Wd_ih,
                  const float* __restrict__ We_hh, const float* __restrict__ Wm_hh,
                  const float* __restrict__ Wd_hh,
                  const float* __restrict__ be_hh, const float* __restrict__ bm_hh,
                  const float* __restrict__ bd_hh, const float* __restrict__ bd_ih,
                  const float* __restrict__ W_dec, const float* __restrict__ b_dec,
                  float* __restrict__ recon, float* __restrict__ h_dec0) {
  const int b = blockIdx.x, tid = threadIdx.x, wv = tid >> 6, g = tid & 63;
  __shared__ __align__(16) _Float16 h1h[2][HH], h2h[2][HH], h3h[2][HH];
  __shared__ __align__(16) float h3f[2][HH];
  __shared__ __align__(16) float q2[2][GG], q3[2][GG];

  half2_t wa[32], wb[32], wc[32];   // packed f16 weight rows (roles 0..4)
  float wdec[64];                   // fp32 recon row (role 5)
  if (wv == 0) {
    loadroww_(wa, We_hh + (size_t)g * HH);
    loadroww_(wb, We_hh + (size_t)(g + 64) * HH);
    loadroww_(wc, We_hh + (size_t)(g + 128) * HH);
  } else if (wv == 1) {      // Wm_ih [192][128], cols 0..63 (h_out part)
    loadroww_(wa, Wm_ih + (size_t)g * 128);
    loadroww_(wb, Wm_ih + (size_t)(g + 64) * 128);
    loadroww_(wc, Wm_ih + (size_t)(g + 128) * 128);
  } else if (wv == 2) {
    loadroww_(wa, Wm_hh + (size_t)g * HH);
    loadroww_(wb, Wm_hh + (size_t)(g + 64) * HH);
    loadroww_(wc, Wm_hh + (size_t)(g + 128) * HH);
  } else if (wv == 3) {      // Wd_ih [192][64]
    loadroww_(wa, Wd_ih + (size_t)g * HH);
    loadroww_(wb, Wd_ih + (size_t)(g + 64) * HH);
    loadroww_(wc, Wd_ih + (size_t)(g + 128) * HH);
  } else if (wv == 4) {
    loadroww_(wa, Wd_hh + (size_t)g * HH);
    loadroww_(wb, Wd_hh + (size_t)(g + 64) * HH);
    loadroww_(wc, Wd_hh + (size_t)(g + 128) * HH);
  } else {
    loadrow_(wdec, W_dec + (size_t)g * HH);
  }
  float bh0 = 0.f, bh1 = 0.f, bh2 = 0.f;
  if (wv == 0) { bh0 = be_hh[g]; bh1 = be_hh[64 + g]; bh2 = be_hh[128 + g]; }
  if (wv == 2) { bh0 = bm_hh[g]; bh1 = bm_hh[64 + g]; bh2 = bm_hh[128 + g]; }
  if (wv == 4) { bh0 = bd_hh[g]; bh1 = bd_hh[64 + g]; bh2 = bd_hh[128 + g]; }
  float bi0 = 0.f, bi1 = 0.f, bi2 = 0.f;
  if (wv == 4) { bi0 = bd_ih[g]; bi1 = bd_ih[64 + g]; bi2 = bd_ih[128 + g]; }
  float bdc = (wv == 5) ? b_dec[g] : 0.f;

  if (wv == 0) {
    h1h[1][g] = (_Float16)0.f; h2h[1][g] = (_Float16)0.f; h3h[1][g] = (_Float16)0.f;
    h3f[1][g] = 0.f;
  }
  __syncthreads();

  const float* gi1p = gi1 + (size_t)b * TT * GG;
  const float* pc2p = pc2 + (size_t)b * TT * GG;
  float hown = 0.f;
  // prefetch registers (wave 0: gi1[t]; wave 2: pc2[t])
  float cr = 0.f, cz = 0.f, cn = 0.f;
  if (wv == 0) { cr = gi1p[g]; cz = gi1p[64 + g]; cn = gi1p[128 + g]; }
  if (wv == 2) { cr = pc2p[g]; cz = pc2p[64 + g]; cn = pc2p[128 + g]; }

  for (int ph = 0; ph < TT + 5; ++ph) {
    const int pw = ph & 1, pr = (ph - 1) & 1;
    if (wv == 0) {
      int t = ph;
      if (t < TT) {
        float nr = 0.f, nz = 0.f, nn_ = 0.f;
        if (t + 1 < TT) {  // issue next-t loads first (latency hides under matvec)
          const float* p = gi1p + (size_t)(t + 1) * GG;
          nr = p[g]; nz = p[64 + g]; nn_ = p[128 + g];
        }
        half2_t hp[32];
        load_h16_(&h1h[pr][0], hp);
        float a0 = bh0, a1 = bh1, a2 = bh2;
        mvdot3_(hp, wa, wb, wc, a0, a1, a2);
        float r = fsig_(cr + a0), z = fsig_(cz + a1), n = ftanh_(cn + r * a2);
        hown = fmaf(z, hown - n, n);
        h1h[pw][g] = (_Float16)hown;
        cr = nr; cz = nz; cn = nn_;
      }
    } else if (wv == 1) {
      if (ph >= 1 && ph <= TT) {
        half2_t hp[32];
        load_h16_(&h1h[pr][0], hp);
        float a0 = 0.f, a1 = 0.f, a2 = 0.f;
        mvdot3_(hp, wa, wb, wc, a0, a1, a2);
        q2[pw][g] = a0; q2[pw][64 + g] = a1; q2[pw][128 + g] = a2;
      }
    } else if (wv == 2) {
      int t = ph - 2;
      if (t >= 0 && t < TT) {
        float nr = 0.f, nz = 0.f, nn_ = 0.f;
        if (t + 1 < TT) {
          const float* p = pc2p + (size_t)(t + 1) * GG;
          nr = p[g]; nz = p[64 + g]; nn_ = p[128 + g];
        }
        half2_t hp[32];
        load_h16_(&h2h[pr][0], hp);
        float a0 = bh0, a1 = bh1, a2 = bh2;
        mvdot3_(hp, wa, wb, wc, a0, a1, a2);
        float gr = q2[pr][g] + cr, gz = q2[pr][64 + g] + cz, gn = q2[pr][128 + g] + cn;
        float r = fsig_(gr + a0), z = fsig_(gz + a1), n = ftanh_(gn + r * a2);
        hown = fmaf(z, hown - n, n);
        h2h[pw][g] = (_Float16)hown;
        cr = nr; cz = nz; cn = nn_;
      }
    } else if (wv == 3) {
      if (ph >= 3 && ph <= TT + 2) {
        half2_t hp[32];
        load_h16_(&h2h[pr][0], hp);
        float a0 = 0.f, a1 = 0.f, a2 = 0.f;
        mvdot3_(hp, wa, wb, wc, a0, a1, a2);
        q3[pw][g] = a0; q3[pw][64 + g] = a1; q3[pw][128 + g] = a2;
      }
    } else if (wv == 4) {
      int t = ph - 4;
      if (t >= 0 && t < TT) {
        half2_t hp[32];
        load_h16_(&h3h[pr][0], hp);
        float a0 = bh0, a1 = bh1, a2 = bh2;
        mvdot3_(hp, wa, wb, wc, a0, a1, a2);
        float gr = q3[pr][g] + bi0, gz = q3[pr][64 + g] + bi1, gn = q3[pr][128 + g] + bi2;
        float r = fsig_(gr + a0), z = fsig_(gz + a1), n = ftanh_(gn + r * a2);
        hown = fmaf(z, hown - n, n);
        h3h[pw][g] = (_Float16)hown;
        h3f[pw][g] = hown;
        if (t == 0) h_dec0[(size_t)b * HH + g] = hown;
      }
    } else {
      int t = ph - 5;
      if (t >= 0) {
        const float4* h4 = (const float4*)&h3f[pr][0];
        float a0 = bdc, a1 = 0.f;
        #pragma unroll
        for (int i = 0; i < 8; ++i) {
          float4 hv = h4[2 * i], hw = h4[2 * i + 1];
          a0 = fmaf(hv.x, wdec[8*i],   fmaf(hv.y, wdec[8*i+1], fmaf(hv.z, wdec[8*i+2], fmaf(hv.w, wdec[8*i+3], a0))));
          a1 = fmaf(hw.x, wdec[8*i+4], fmaf(hw.y, wdec[8*i+5], fmaf(hw.z, wdec[8*i+6], fmaf(hw.w, wdec[8*i+7], a1))));
        }
        recon[((size_t)b * TT + t) * NN + g] = a0 + a1;
      }
    }
    __syncthreads();
  }
}

// pred head: p = relu(W_p1 @ h0 + b_p1); pred = W_p2 @ p + b_p2. 64 blocks x 64 thr.
__global__ void phead_kernel(const float* __restrict__ h0, const float* __restrict__ W_p1,
                             const float* __restrict__ b_p1, const float* __restrict__ W_p2,
                             const float* __restrict__ b_p2, float* __restrict__ pred) {
  const int b = blockIdx.x, g = threadIdx.x;
  __shared__ __align__(16) float hb[HH], ps[HH];
  hb[g] = h0[(size_t)b * HH + g];
  __syncthreads();
  const float* w1 = W_p1 + (size_t)g * HH;
  float a = b_p1[g];
  #pragma unroll 8
  for (int k = 0; k < HH; ++k) a += hb[k] * w1[k];
  ps[g] = fmaxf(a, 0.f);
  __syncthreads();
  const float* w2 = W_p2 + (size_t)g * HH;
  float c = b_p2[g];
  #pragma unroll 8
  for (int k = 0; k < HH; ++k) c += ps[k] * w2[k];
  pred[(size_t)b * NN + g] = c;
}

extern "C" void kernel_launch(void* const* d_in, const int* in_sizes, int n_in,
                              void* d_out, int out_size, void* d_ws, size_t ws_size,
                              hipStream_t stream) {
  const float* x      = (const float*)d_in[0];
  const float* conv_w = (const float*)d_in[2];
  const float* conv_b = (const float*)d_in[3];
  const float* We_ih  = (const float*)d_in[4];
  const float* We_hh  = (const float*)d_in[5];
  const float* be_ih  = (const float*)d_in[6];
  const float* be_hh  = (const float*)d_in[7];
  const float* Ww     = (const float*)d_in[8];
  const float* bw     = (const float*)d_in[9];
  const float* Wa     = (const float*)d_in[10];
  const float* ba     = (const float*)d_in[11];
  const float* Wm_ih  = (const float*)d_in[12];
  const float* Wm_hh  = (const float*)d_in[13];
  const float* bm_ih  = (const float*)d_in[14];
  const float* bm_hh  = (const float*)d_in[15];
  const float* Wd_ih  = (const float*)d_in[16];
  const float* Wd_hh  = (const float*)d_in[17];
  const float* bd_ih  = (const float*)d_in[18];
  const float* bd_hh  = (const float*)d_in[19];
  const float* W_dec  = (const float*)d_in[20];
  const float* b_dec  = (const float*)d_in[21];
  const float* W_p1   = (const float*)d_in[22];
  const float* b_p1   = (const float*)d_in[23];
  const float* W_p2   = (const float*)d_in[24];
  const float* b_p2   = (const float*)d_in[25];
  float* out = (float*)d_out;

  float* wsf   = (float*)d_ws;
  float* c_nt  = wsf;                 // B*N*T    = 524288
  float* c_btn = c_nt  + 524288;      // B*T*N    = 524288
  float* s1    = c_btn + 524288;      // B*N*E    = 524288
  float* s2    = s1    + 524288;      // B*N*E    = 524288
  float* hmp   = s2    + 524288;      // B*T*N    = 524288
  float* pc2   = hmp   + 524288;      // B*T*3H   = 1572864
  float* gi1   = pc2   + 1572864;     // B*T*3H   = 1572864
  float* hd0   = gi1   + 1572864;     // B*H      = 4096

  conv_selu_kernel<<<dim3(8, BB), 128, 0, stream>>>(x, conv_w, conv_b, c_nt, c_btn);
  s12_kernel<<<BB * NN / 16, 128, 0, stream>>>(c_nt, Ww, s1, s2);
  gat_kernel<<<dim3(NN, BB), 128, 0, stream>>>(s1, s2, bw, Wa, ba, c_nt, hmp);
  linear_tiled<GG, NN, 16, 0><<<BB * TT / 16, GG, 0, stream>>>(c_btn, NN, We_ih, NN, 0, be_ih, gi1, GG);
  linear_tiled<GG, NN, 16, 0><<<BB * TT / 16, GG, 0, stream>>>(hmp, NN, Wm_ih, 2 * NN, NN, bm_ih, pc2, GG);
  // fused 3-GRU + recon, 6-wave skewed pipeline
  fused_chain6<<<BB, 384, 0, stream>>>(gi1, pc2, Wm_ih, Wd_ih, We_hh, Wm_hh, Wd_hh,
                                       be_hh, bm_hh, bd_hh, bd_ih, W_dec, b_dec,
                                       out, hd0);
  // pred head
  phead_kernel<<<BB, 64, 0, stream>>>(hd0, W_p1, b_p1, W_p2, b_p2, out + BB * TT * NN);
}

// Round 7
// 237.481 us; speedup vs baseline: 3.1452x; 1.0079x over previous
//
#include <hip/hip_runtime.h>
#include <math.h>

#define BB 64
#define TT 128
#define NN 64
#define HH 64
#define EE 128
#define KK 7
#define GG 192  // 3*H

typedef _Float16 half2_t __attribute__((ext_vector_type(2)));

__device__ __forceinline__ float sigmoidf_(float x){ return 1.f/(1.f+expf(-x)); }
__device__ __forceinline__ float fsig_(float x){ return __frcp_rn(1.f + __expf(-x)); }
__device__ __forceinline__ float ftanh_(float x){ return 2.f * __frcp_rn(1.f + __expf(-2.f * x)) - 1.f; }

// Phase barrier: order LDS handoffs only. NO vmcnt drain — global prefetch loads
// stay in flight across the barrier (T4); compiler tracks their consumption.
#define PIPE_BARRIER() asm volatile("s_waitcnt lgkmcnt(0)\ns_barrier" ::: "memory")

__device__ __forceinline__ void loadrow_(float* d, const float* src){
  const float4* p = (const float4*)src;
  #pragma unroll
  for (int i = 0; i < 16; ++i) {
    float4 v = p[i];
    d[4*i] = v.x; d[4*i+1] = v.y; d[4*i+2] = v.z; d[4*i+3] = v.w;
  }
}
// load 64 fp32 weights -> 32 packed f16 pairs (RNE converts)
__device__ __forceinline__ void loadroww_(half2_t* d, const float* src){
  const float4* p = (const float4*)src;
  #pragma unroll
  for (int i = 0; i < 16; ++i) {
    float4 v = p[i];
    d[2*i]   = half2_t{(_Float16)v.x, (_Float16)v.y};
    d[2*i+1] = half2_t{(_Float16)v.z, (_Float16)v.w};
  }
}
// read 64 f16 values (128B) from LDS as 32 packed pairs via b128 chunks
__device__ __forceinline__ void load_h16_(const _Float16* hs, half2_t* hp){
  const float4* s4 = (const float4*)hs;
  #pragma unroll
  for (int j = 0; j < 8; ++j) {
    float4 v = s4[j];
    const half2_t* q = (const half2_t*)&v;
    hp[4*j] = q[0]; hp[4*j+1] = q[1]; hp[4*j+2] = q[2]; hp[4*j+3] = q[3];
  }
}
// 3-row matvec via v_dot2_f32_f16 (fp32 accumulate)
__device__ __forceinline__ void mvdot3_(const half2_t* hp, const half2_t* w0,
                                        const half2_t* w1, const half2_t* w2,
                                        float& a0, float& a1, float& a2){
  #pragma unroll
  for (int i = 0; i < 32; ++i) {
    a0 = __builtin_amdgcn_fdot2(hp[i], w0[i], a0, false);
    a1 = __builtin_amdgcn_fdot2(hp[i], w1[i], a1, false);
    a2 = __builtin_amdgcn_fdot2(hp[i], w2[i], a2, false);
  }
}

// Conv1d (N->N, K=7, pad same) + SELU. 8 output channels per block.
__global__ void conv_selu_kernel(const float* __restrict__ x, const float* __restrict__ w,
                                 const float* __restrict__ bias,
                                 float* __restrict__ c_nt, float* __restrict__ c_btn) {
  const int og = blockIdx.x, b = blockIdx.y, t = threadIdx.x;
  const int o0 = og * 8;
  __shared__ __align__(16) float xs[NN][TT + 1];
  __shared__ __align__(16) float ws[NN * KK][8];
  for (int idx = t; idx < TT * NN; idx += 128) {
    int tt = idx >> 6, nn = idx & 63;
    xs[nn][tt] = x[(size_t)(b * TT + tt) * NN + nn];
  }
  for (int idx = t; idx < NN * KK * 8; idx += 128) {
    int oo = idx & 7, ik = idx >> 3;
    ws[ik][oo] = w[(size_t)(o0 + oo) * (NN * KK) + ik];
  }
  __syncthreads();
  float acc[8];
  #pragma unroll
  for (int oo = 0; oo < 8; ++oo) acc[oo] = bias[o0 + oo];
  for (int i = 0; i < NN; ++i) {
    #pragma unroll
    for (int k = 0; k < KK; ++k) {
      int tt = t + k - 3;
      if (tt >= 0 && tt < TT) {
        float xv = xs[i][tt];
        const float* wp = &ws[i * KK + k][0];
        float4 w0 = *(const float4*)wp;
        float4 w1 = *(const float4*)(wp + 4);
        acc[0] += xv * w0.x; acc[1] += xv * w0.y; acc[2] += xv * w0.z; acc[3] += xv * w0.w;
        acc[4] += xv * w1.x; acc[5] += xv * w1.y; acc[6] += xv * w1.z; acc[7] += xv * w1.w;
      }
    }
  }
  const float alpha = 1.6732632423543772f, scale = 1.0507009873554805f;
  #pragma unroll
  for (int oo = 0; oo < 8; ++oo) {
    float a = acc[oo];
    float r = a > 0.f ? scale * a : scale * alpha * expm1f(a);
    int o = o0 + oo;
    c_nt[((size_t)b * NN + o) * TT + t] = r;
    c_btn[((size_t)b * TT + t) * NN + o] = r;
  }
}

// Dual K=64 projection: y=0 -> gi1 = We_ih @ c_btn + be_ih ; y=1 -> pc2 = Wm_ih[:,64:] @ hmp + bm_ih
__global__ void gi_dual_kernel(const float* __restrict__ c_btn, const float* __restrict__ hmp,
                               const float* __restrict__ We_ih, const float* __restrict__ Wm_ih,
                               const float* __restrict__ be_ih, const float* __restrict__ bm_ih,
                               float* __restrict__ gi1, float* __restrict__ pc2) {
  const int m0 = blockIdx.x * 16, col = threadIdx.x, which = blockIdx.y;
  const float* in = which ? hmp : c_btn;
  const float* W  = which ? (Wm_ih + NN) : We_ih;
  const int wstride = which ? 2 * NN : NN;
  const float* bias = which ? bm_ih : be_ih;
  float* out = which ? pc2 : gi1;
  __shared__ __align__(16) float ins[16][NN];
  for (int idx = col; idx < 16 * NN; idx += GG) {
    int r = idx >> 6, k = idx & 63;
    ins[r][k] = in[(size_t)(m0 + r) * NN + k];
  }
  __syncthreads();
  const float* wr = W + (size_t)col * wstride;
  float bv = bias[col];
  float acc[16];
  #pragma unroll
  for (int r = 0; r < 16; ++r) acc[r] = bv;
  #pragma unroll 2
  for (int k = 0; k < NN; k += 4) {
    float4 wv = *(const float4*)(wr + k);
    #pragma unroll
    for (int r = 0; r < 16; ++r) {
      float4 iv = *(const float4*)&ins[r][k];
      acc[r] += iv.x * wv.x + iv.y * wv.y + iv.z * wv.z + iv.w * wv.w;
    }
  }
  #pragma unroll
  for (int r = 0; r < 16; ++r)
    out[(size_t)(m0 + r) * GG + col] = acc[r];
}

// Fused s1 + s2 projection
__global__ void s12_kernel(const float* __restrict__ c_nt, const float* __restrict__ Ww,
                           float* __restrict__ s1, float* __restrict__ s2) {
  const int m0 = blockIdx.x * 16, col = threadIdx.x;  // 128 threads
  __shared__ __align__(16) float ins[16][TT];
  for (int idx = col; idx < 16 * TT; idx += 128) {
    int r = idx >> 7, k = idx & 127;
    ins[r][k] = c_nt[(size_t)(m0 + r) * TT + k];
  }
  __syncthreads();
  const float* w1 = Ww + (size_t)col * (2 * TT);
  const float* w2 = w1 + TT;
  float acc1[16], acc2[16];
  #pragma unroll
  for (int r = 0; r < 16; ++r) { acc1[r] = 0.f; acc2[r] = 0.f; }
  #pragma unroll 2
  for (int k = 0; k < TT; k += 4) {
    float4 wv1 = *(const float4*)(w1 + k);
    float4 wv2 = *(const float4*)(w2 + k);
    #pragma unroll
    for (int r = 0; r < 16; ++r) {
      float4 iv = *(const float4*)&ins[r][k];
      acc1[r] += iv.x * wv1.x + iv.y * wv1.y + iv.z * wv1.z + iv.w * wv1.w;
      acc2[r] += iv.x * wv2.x + iv.y * wv2.y + iv.z * wv2.z + iv.w * wv2.w;
    }
  }
  #pragma unroll
  for (int r = 0; r < 16; ++r) {
    s1[(size_t)(m0 + r) * EE + col] = acc1[r];
    s2[(size_t)(m0 + r) * EE + col] = acc2[r];
  }
}

// GAT -> compact h_mp [B,T,N]
__global__ void gat_kernel(const float* __restrict__ s1, const float* __restrict__ s2,
                           const float* __restrict__ bw, const float* __restrict__ Wa,
                           const float* __restrict__ ba, const float* __restrict__ c_nt,
                           float* __restrict__ hmp) {
  const int i = blockIdx.x, b = blockIdx.y, tid = threadIdx.x;  // 128 threads
  __shared__ float s2s[NN][EE + 1];
  __shared__ float s1b[EE], was[EE], att[NN];
  for (int idx = tid; idx < NN * EE; idx += 128) {
    int r = idx >> 7, e = idx & 127;
    s2s[r][e] = s2[((size_t)b * NN + r) * EE + e];
  }
  s1b[tid] = s1[((size_t)b * NN + i) * EE + tid] + bw[tid];
  was[tid] = Wa[tid];
  __syncthreads();
  if (tid < NN) {
    float acc = 0.f;
    #pragma unroll 8
    for (int e = 0; e < EE; ++e) {
      float wv = s1b[e] + s2s[tid][e];
      wv = wv > 0.f ? wv : 0.2f * wv;
      acc += was[e] * wv;
    }
    float ej = acc + ba[0];
    float mx = ej;
    for (int off = 32; off >= 1; off >>= 1) mx = fmaxf(mx, __shfl_xor(mx, off));
    float ex = expf(ej - mx);
    float sm = ex;
    for (int off = 32; off >= 1; off >>= 1) sm += __shfl_xor(sm, off);
    att[tid] = ex / sm;
  }
  __syncthreads();
  float acc = 0.f;
  #pragma unroll 8
  for (int j = 0; j < NN; ++j) acc += att[j] * c_nt[((size_t)b * NN + j) * TT + tid];
  hmp[((size_t)b * TT + tid) * NN + i] = sigmoidf_(acc);
}

// Fused 3-GRU + recon head, 6-wave skewed pipeline (one block per batch).
// Roles: w0=rec1, w1=proj1->2, w2=rec2, w3=proj2->3, w4=rec3, w5=recon.
// f16 dot2 matvecs; fp32 recurrence state. Depth-2 global prefetch; raw
// lgkm-only phase barriers keep prefetch loads in flight (no vmcnt drain).
__global__ __launch_bounds__(384, 1)
void fused_chain6(const float* __restrict__ gi1, const float* __restrict__ pc2,
                  const float* __restrict__ Wm_ih, const float* __restrict__ Wd_ih,
                  const float* __restrict__ We_hh, const float* __restrict__ Wm_hh,
                  const float* __restrict__ Wd_hh,
                  const float* __restrict__ be_hh, const float* __restrict__ bm_hh,
                  const float* __restrict__ bd_hh, const float* __restrict__ bd_ih,
                  const float* __restrict__ W_dec, const float* __restrict__ b_dec,
                  float* __restrict__ recon, float* __restrict__ h_dec0) {
  const int b = blockIdx.x, tid = threadIdx.x, wv = tid >> 6, g = tid & 63;
  __shared__ __align__(16) _Float16 h1h[2][HH], h2h[2][HH], h3h[2][HH];
  __shared__ __align__(16) float h3f[2][HH];
  __shared__ __align__(16) float q2[2][GG], q3[2][GG];

  half2_t wa[32], wb[32], wc[32];   // packed f16 weight rows (roles 0..4)
  float wdec[64];                   // fp32 recon row (role 5)
  if (wv == 0) {
    loadroww_(wa, We_hh + (size_t)g * HH);
    loadroww_(wb, We_hh + (size_t)(g + 64) * HH);
    loadroww_(wc, We_hh + (size_t)(g + 128) * HH);
  } else if (wv == 1) {      // Wm_ih [192][128], cols 0..63 (h_out part)
    loadroww_(wa, Wm_ih + (size_t)g * 128);
    loadroww_(wb, Wm_ih + (size_t)(g + 64) * 128);
    loadroww_(wc, Wm_ih + (size_t)(g + 128) * 128);
  } else if (wv == 2) {
    loadroww_(wa, Wm_hh + (size_t)g * HH);
    loadroww_(wb, Wm_hh + (size_t)(g + 64) * HH);
    loadroww_(wc, Wm_hh + (size_t)(g + 128) * HH);
  } else if (wv == 3) {      // Wd_ih [192][64]
    loadroww_(wa, Wd_ih + (size_t)g * HH);
    loadroww_(wb, Wd_ih + (size_t)(g + 64) * HH);
    loadroww_(wc, Wd_ih + (size_t)(g + 128) * HH);
  } else if (wv == 4) {
    loadroww_(wa, Wd_hh + (size_t)g * HH);
    loadroww_(wb, Wd_hh + (size_t)(g + 64) * HH);
    loadroww_(wc, Wd_hh + (size_t)(g + 128) * HH);
  } else {
    loadrow_(wdec, W_dec + (size_t)g * HH);
  }
  float bh0 = 0.f, bh1 = 0.f, bh2 = 0.f;
  if (wv == 0) { bh0 = be_hh[g]; bh1 = be_hh[64 + g]; bh2 = be_hh[128 + g]; }
  if (wv == 2) { bh0 = bm_hh[g]; bh1 = bm_hh[64 + g]; bh2 = bm_hh[128 + g]; }
  if (wv == 4) { bh0 = bd_hh[g]; bh1 = bd_hh[64 + g]; bh2 = bd_hh[128 + g]; }
  float bi0 = 0.f, bi1 = 0.f, bi2 = 0.f;
  if (wv == 4) { bi0 = bd_ih[g]; bi1 = bd_ih[64 + g]; bi2 = bd_ih[128 + g]; }
  float bdc = (wv == 5) ? b_dec[g] : 0.f;

  if (wv == 0) {
    h1h[1][g] = (_Float16)0.f; h2h[1][g] = (_Float16)0.f; h3h[1][g] = (_Float16)0.f;
    h3f[1][g] = 0.f;
  }
  __syncthreads();

  const float* gi1p = gi1 + (size_t)b * TT * GG;
  const float* pc2p = pc2 + (size_t)b * TT * GG;
  float hown = 0.f;
  // depth-2 prefetch pipeline: c* = t (consume now), n1* = t+1 (in flight)
  float cr = 0.f, cz = 0.f, cn = 0.f, n1r = 0.f, n1z = 0.f, n1n = 0.f;
  if (wv == 0) {
    cr = gi1p[g]; cz = gi1p[64 + g]; cn = gi1p[128 + g];
    n1r = gi1p[GG + g]; n1z = gi1p[GG + 64 + g]; n1n = gi1p[GG + 128 + g];
  }
  if (wv == 2) {
    cr = pc2p[g]; cz = pc2p[64 + g]; cn = pc2p[128 + g];
    n1r = pc2p[GG + g]; n1z = pc2p[GG + 64 + g]; n1n = pc2p[GG + 128 + g];
  }

  for (int ph = 0; ph < TT + 5; ++ph) {
    const int pw = ph & 1, pr = (ph - 1) & 1;
    if (wv == 0) {
      int t = ph;
      if (t < TT) {
        float n2r = 0.f, n2z = 0.f, n2n = 0.f;
        if (t + 2 < TT) {  // issue t+2 loads; consumed 2 phases later
          const float* p = gi1p + (size_t)(t + 2) * GG;
          n2r = p[g]; n2z = p[64 + g]; n2n = p[128 + g];
        }
        half2_t hp[32];
        load_h16_(&h1h[pr][0], hp);
        float a0 = bh0, a1 = bh1, a2 = bh2;
        mvdot3_(hp, wa, wb, wc, a0, a1, a2);
        float r = fsig_(cr + a0), z = fsig_(cz + a1), n = ftanh_(cn + r * a2);
        hown = fmaf(z, hown - n, n);
        h1h[pw][g] = (_Float16)hown;
        cr = n1r; cz = n1z; cn = n1n; n1r = n2r; n1z = n2z; n1n = n2n;
      }
    } else if (wv == 1) {
      if (ph >= 1 && ph <= TT) {
        half2_t hp[32];
        load_h16_(&h1h[pr][0], hp);
        float a0 = 0.f, a1 = 0.f, a2 = 0.f;
        mvdot3_(hp, wa, wb, wc, a0, a1, a2);
        q2[pw][g] = a0; q2[pw][64 + g] = a1; q2[pw][128 + g] = a2;
      }
    } else if (wv == 2) {
      int t = ph - 2;
      if (t >= 0 && t < TT) {
        float n2r = 0.f, n2z = 0.f, n2n = 0.f;
        if (t + 2 < TT) {
          const float* p = pc2p + (size_t)(t + 2) * GG;
          n2r = p[g]; n2z = p[64 + g]; n2n = p[128 + g];
        }
        half2_t hp[32];
        load_h16_(&h2h[pr][0], hp);
        float a0 = bh0, a1 = bh1, a2 = bh2;
        mvdot3_(hp, wa, wb, wc, a0, a1, a2);
        float gr = q2[pr][g] + cr, gz = q2[pr][64 + g] + cz, gn = q2[pr][128 + g] + cn;
        float r = fsig_(gr + a0), z = fsig_(gz + a1), n = ftanh_(gn + r * a2);
        hown = fmaf(z, hown - n, n);
        h2h[pw][g] = (_Float16)hown;
        cr = n1r; cz = n1z; cn = n1n; n1r = n2r; n1z = n2z; n1n = n2n;
      }
    } else if (wv == 3) {
      if (ph >= 3 && ph <= TT + 2) {
        half2_t hp[32];
        load_h16_(&h2h[pr][0], hp);
        float a0 = 0.f, a1 = 0.f, a2 = 0.f;
        mvdot3_(hp, wa, wb, wc, a0, a1, a2);
        q3[pw][g] = a0; q3[pw][64 + g] = a1; q3[pw][128 + g] = a2;
      }
    } else if (wv == 4) {
      int t = ph - 4;
      if (t >= 0 && t < TT) {
        half2_t hp[32];
        load_h16_(&h3h[pr][0], hp);
        float a0 = bh0, a1 = bh1, a2 = bh2;
        mvdot3_(hp, wa, wb, wc, a0, a1, a2);
        float gr = q3[pr][g] + bi0, gz = q3[pr][64 + g] + bi1, gn = q3[pr][128 + g] + bi2;
        float r = fsig_(gr + a0), z = fsig_(gz + a1), n = ftanh_(gn + r * a2);
        hown = fmaf(z, hown - n, n);
        h3h[pw][g] = (_Float16)hown;
        h3f[pw][g] = hown;
        if (t == 0) h_dec0[(size_t)b * HH + g] = hown;
      }
    } else {
      int t = ph - 5;
      if (t >= 0) {
        const float4* h4 = (const float4*)&h3f[pr][0];
        float a0 = bdc, a1 = 0.f;
        #pragma unroll
        for (int i = 0; i < 8; ++i) {
          float4 hv = h4[2 * i], hw = h4[2 * i + 1];
          a0 = fmaf(hv.x, wdec[8*i],   fmaf(hv.y, wdec[8*i+1], fmaf(hv.z, wdec[8*i+2], fmaf(hv.w, wdec[8*i+3], a0))));
          a1 = fmaf(hw.x, wdec[8*i+4], fmaf(hw.y, wdec[8*i+5], fmaf(hw.z, wdec[8*i+6], fmaf(hw.w, wdec[8*i+7], a1))));
        }
        recon[((size_t)b * TT + t) * NN + g] = a0 + a1;
      }
    }
    PIPE_BARRIER();
  }
}

// pred head: p = relu(W_p1 @ h0 + b_p1); pred = W_p2 @ p + b_p2. 64 blocks x 64 thr.
__global__ void phead_kernel(const float* __restrict__ h0, const float* __restrict__ W_p1,
                             const float* __restrict__ b_p1, const float* __restrict__ W_p2,
                             const float* __restrict__ b_p2, float* __restrict__ pred) {
  const int b = blockIdx.x, g = threadIdx.x;
  __shared__ __align__(16) float hb[HH], ps[HH];
  hb[g] = h0[(size_t)b * HH + g];
  __syncthreads();
  const float* w1 = W_p1 + (size_t)g * HH;
  float a = b_p1[g];
  #pragma unroll 8
  for (int k = 0; k < HH; ++k) a += hb[k] * w1[k];
  ps[g] = fmaxf(a, 0.f);
  __syncthreads();
  const float* w2 = W_p2 + (size_t)g * HH;
  float c = b_p2[g];
  #pragma unroll 8
  for (int k = 0; k < HH; ++k) c += ps[k] * w2[k];
  pred[(size_t)b * NN + g] = c;
}

extern "C" void kernel_launch(void* const* d_in, const int* in_sizes, int n_in,
                              void* d_out, int out_size, void* d_ws, size_t ws_size,
                              hipStream_t stream) {
  const float* x      = (const float*)d_in[0];
  const float* conv_w = (const float*)d_in[2];
  const float* conv_b = (const float*)d_in[3];
  const float* We_ih  = (const float*)d_in[4];
  const float* We_hh  = (const float*)d_in[5];
  const float* be_ih  = (const float*)d_in[6];
  const float* be_hh  = (const float*)d_in[7];
  const float* Ww     = (const float*)d_in[8];
  const float* bw     = (const float*)d_in[9];
  const float* Wa     = (const float*)d_in[10];
  const float* ba     = (const float*)d_in[11];
  const float* Wm_ih  = (const float*)d_in[12];
  const float* Wm_hh  = (const float*)d_in[13];
  const float* bm_ih  = (const float*)d_in[14];
  const float* bm_hh  = (const float*)d_in[15];
  const float* Wd_ih  = (const float*)d_in[16];
  const float* Wd_hh  = (const float*)d_in[17];
  const float* bd_ih  = (const float*)d_in[18];
  const float* bd_hh  = (const float*)d_in[19];
  const float* W_dec  = (const float*)d_in[20];
  const float* b_dec  = (const float*)d_in[21];
  const float* W_p1   = (const float*)d_in[22];
  const float* b_p1   = (const float*)d_in[23];
  const float* W_p2   = (const float*)d_in[24];
  const float* b_p2   = (const float*)d_in[25];
  float* out = (float*)d_out;

  float* wsf   = (float*)d_ws;
  float* c_nt  = wsf;                 // B*N*T    = 524288
  float* c_btn = c_nt  + 524288;      // B*T*N    = 524288
  float* s1    = c_btn + 524288;      // B*N*E    = 524288
  float* s2    = s1    + 524288;      // B*N*E    = 524288
  float* hmp   = s2    + 524288;      // B*T*N    = 524288
  float* pc2   = hmp   + 524288;      // B*T*3H   = 1572864
  float* gi1   = pc2   + 1572864;     // B*T*3H   = 1572864
  float* hd0   = gi1   + 1572864;     // B*H      = 4096

  conv_selu_kernel<<<dim3(8, BB), 128, 0, stream>>>(x, conv_w, conv_b, c_nt, c_btn);
  s12_kernel<<<BB * NN / 16, 128, 0, stream>>>(c_nt, Ww, s1, s2);
  gat_kernel<<<dim3(NN, BB), 128, 0, stream>>>(s1, s2, bw, Wa, ba, c_nt, hmp);
  gi_dual_kernel<<<dim3(BB * TT / 16, 2), GG, 0, stream>>>(c_btn, hmp, We_ih, Wm_ih,
                                                           be_ih, bm_ih, gi1, pc2);
  // fused 3-GRU + recon, 6-wave skewed pipeline
  fused_chain6<<<BB, 384, 0, stream>>>(gi1, pc2, Wm_ih, Wd_ih, We_hh, Wm_hh, Wd_hh,
                                       be_hh, bm_hh, bd_hh, bd_ih, W_dec, b_dec,
                                       out, hd0);
  // pred head
  phead_kernel<<<BB, 64, 0, stream>>>(hd0, W_p1, b_p1, W_p2, b_p2, out + BB * TT * NN);
}

// Round 8
// 205.957 us; speedup vs baseline: 3.6266x; 1.1531x over previous
//
#include <hip/hip_runtime.h>
#include <math.h>

#define BB 64
#define TT 128
#define NN 64
#define HH 64
#define EE 128
#define KK 7
#define GG 192  // 3*H

typedef _Float16 half2_t __attribute__((ext_vector_type(2)));

__device__ __forceinline__ float sigmoidf_(float x){ return 1.f/(1.f+expf(-x)); }
// fast gates: v_exp_f32 (2^x) + v_rcp_f32 single instrs — NOT the IEEE div sequence
__device__ __forceinline__ float fsig_(float x){
  return __builtin_amdgcn_rcpf(1.f + __builtin_amdgcn_exp2f(-1.44269504f * x));
}
__device__ __forceinline__ float ftanh_(float x){
  // tanh(x) = 1 - 2/(1+e^{2x})
  return fmaf(-2.f, __builtin_amdgcn_rcpf(1.f + __builtin_amdgcn_exp2f(2.88539008f * x)), 1.f);
}

// Phase barrier: order LDS handoffs only (no vmcnt drain).
#define PIPE_BARRIER() asm volatile("s_waitcnt lgkmcnt(0)\ns_barrier" ::: "memory")

__device__ __forceinline__ void loadrow_(float* d, const float* src){
  const float4* p = (const float4*)src;
  #pragma unroll
  for (int i = 0; i < 16; ++i) {
    float4 v = p[i];
    d[4*i] = v.x; d[4*i+1] = v.y; d[4*i+2] = v.z; d[4*i+3] = v.w;
  }
}
// load 64 fp32 weights -> 32 packed f16 pairs
__device__ __forceinline__ void loadroww_(half2_t* d, const float* src){
  const float4* p = (const float4*)src;
  #pragma unroll
  for (int i = 0; i < 16; ++i) {
    float4 v = p[i];
    d[2*i]   = half2_t{(_Float16)v.x, (_Float16)v.y};
    d[2*i+1] = half2_t{(_Float16)v.z, (_Float16)v.w};
  }
}
// read 64 f16 (128B) from LDS as 32 packed pairs (uniform-address b128 broadcast)
__device__ __forceinline__ void load_h16_(const _Float16* hs, half2_t* hp){
  const float4* s4 = (const float4*)hs;
  #pragma unroll
  for (int j = 0; j < 8; ++j) {
    float4 v = s4[j];
    const half2_t* q = (const half2_t*)&v;
    hp[4*j] = q[0]; hp[4*j+1] = q[1]; hp[4*j+2] = q[2]; hp[4*j+3] = q[3];
  }
}
// 3-row matvec via v_dot2_f32_f16 (fp32 accumulate)
__device__ __forceinline__ void mvdot3_(const half2_t* hp, const half2_t* w0,
                                        const half2_t* w1, const half2_t* w2,
                                        float& a0, float& a1, float& a2){
  #pragma unroll
  for (int i = 0; i < 32; ++i) {
    a0 = __builtin_amdgcn_fdot2(hp[i], w0[i], a0, false);
    a1 = __builtin_amdgcn_fdot2(hp[i], w1[i], a1, false);
    a2 = __builtin_amdgcn_fdot2(hp[i], w2[i], a2, false);
  }
}

// Conv1d (N->N, K=7, pad same) + SELU. 8 output channels per block.
__global__ void conv_selu_kernel(const float* __restrict__ x, const float* __restrict__ w,
                                 const float* __restrict__ bias,
                                 float* __restrict__ c_nt, float* __restrict__ c_btn) {
  const int og = blockIdx.x, b = blockIdx.y, t = threadIdx.x;
  const int o0 = og * 8;
  __shared__ __align__(16) float xs[NN][TT + 1];
  __shared__ __align__(16) float ws[NN * KK][8];
  for (int idx = t; idx < TT * NN; idx += 128) {
    int tt = idx >> 6, nn = idx & 63;
    xs[nn][tt] = x[(size_t)(b * TT + tt) * NN + nn];
  }
  for (int idx = t; idx < NN * KK * 8; idx += 128) {
    int oo = idx & 7, ik = idx >> 3;
    ws[ik][oo] = w[(size_t)(o0 + oo) * (NN * KK) + ik];
  }
  __syncthreads();
  float acc[8];
  #pragma unroll
  for (int oo = 0; oo < 8; ++oo) acc[oo] = bias[o0 + oo];
  for (int i = 0; i < NN; ++i) {
    #pragma unroll
    for (int k = 0; k < KK; ++k) {
      int tt = t + k - 3;
      if (tt >= 0 && tt < TT) {
        float xv = xs[i][tt];
        const float* wp = &ws[i * KK + k][0];
        float4 w0 = *(const float4*)wp;
        float4 w1 = *(const float4*)(wp + 4);
        acc[0] += xv * w0.x; acc[1] += xv * w0.y; acc[2] += xv * w0.z; acc[3] += xv * w0.w;
        acc[4] += xv * w1.x; acc[5] += xv * w1.y; acc[6] += xv * w1.z; acc[7] += xv * w1.w;
      }
    }
  }
  const float alpha = 1.6732632423543772f, scale = 1.0507009873554805f;
  #pragma unroll
  for (int oo = 0; oo < 8; ++oo) {
    float a = acc[oo];
    float r = a > 0.f ? scale * a : scale * alpha * expm1f(a);
    int o = o0 + oo;
    c_nt[((size_t)b * NN + o) * TT + t] = r;
    c_btn[((size_t)b * TT + t) * NN + o] = r;
  }
}

// Fused s1 + s2 projection
__global__ void s12_kernel(const float* __restrict__ c_nt, const float* __restrict__ Ww,
                           float* __restrict__ s1, float* __restrict__ s2) {
  const int m0 = blockIdx.x * 16, col = threadIdx.x;  // 128 threads
  __shared__ __align__(16) float ins[16][TT];
  for (int idx = col; idx < 16 * TT; idx += 128) {
    int r = idx >> 7, k = idx & 127;
    ins[r][k] = c_nt[(size_t)(m0 + r) * TT + k];
  }
  __syncthreads();
  const float* w1 = Ww + (size_t)col * (2 * TT);
  const float* w2 = w1 + TT;
  float acc1[16], acc2[16];
  #pragma unroll
  for (int r = 0; r < 16; ++r) { acc1[r] = 0.f; acc2[r] = 0.f; }
  #pragma unroll 2
  for (int k = 0; k < TT; k += 4) {
    float4 wv1 = *(const float4*)(w1 + k);
    float4 wv2 = *(const float4*)(w2 + k);
    #pragma unroll
    for (int r = 0; r < 16; ++r) {
      float4 iv = *(const float4*)&ins[r][k];
      acc1[r] += iv.x * wv1.x + iv.y * wv1.y + iv.z * wv1.z + iv.w * wv1.w;
      acc2[r] += iv.x * wv2.x + iv.y * wv2.y + iv.z * wv2.z + iv.w * wv2.w;
    }
  }
  #pragma unroll
  for (int r = 0; r < 16; ++r) {
    s1[(size_t)(m0 + r) * EE + col] = acc1[r];
    s2[(size_t)(m0 + r) * EE + col] = acc2[r];
  }
}

// GAT -> compact h_mp [B,T,N]
__global__ void gat_kernel(const float* __restrict__ s1, const float* __restrict__ s2,
                           const float* __restrict__ bw, const float* __restrict__ Wa,
                           const float* __restrict__ ba, const float* __restrict__ c_nt,
                           float* __restrict__ hmp) {
  const int i = blockIdx.x, b = blockIdx.y, tid = threadIdx.x;  // 128 threads
  __shared__ float s2s[NN][EE + 1];
  __shared__ float s1b[EE], was[EE], att[NN];
  for (int idx = tid; idx < NN * EE; idx += 128) {
    int r = idx >> 7, e = idx & 127;
    s2s[r][e] = s2[((size_t)b * NN + r) * EE + e];
  }
  s1b[tid] = s1[((size_t)b * NN + i) * EE + tid] + bw[tid];
  was[tid] = Wa[tid];
  __syncthreads();
  if (tid < NN) {
    float acc = 0.f;
    #pragma unroll 8
    for (int e = 0; e < EE; ++e) {
      float wv = s1b[e] + s2s[tid][e];
      wv = wv > 0.f ? wv : 0.2f * wv;
      acc += was[e] * wv;
    }
    float ej = acc + ba[0];
    float mx = ej;
    for (int off = 32; off >= 1; off >>= 1) mx = fmaxf(mx, __shfl_xor(mx, off));
    float ex = expf(ej - mx);
    float sm = ex;
    for (int off = 32; off >= 1; off >>= 1) sm += __shfl_xor(sm, off);
    att[tid] = ex / sm;
  }
  __syncthreads();
  float acc = 0.f;
  #pragma unroll 8
  for (int j = 0; j < NN; ++j) acc += att[j] * c_nt[((size_t)b * NN + j) * TT + tid];
  hmp[((size_t)b * TT + tid) * NN + i] = sigmoidf_(acc);
}

// Fused {gi1-proj, rec1, p1->2, pc2-proj, rec2, p2->3, rec3, recon} 8-wave skewed
// pipeline, one block per batch + pred head on wave 0 at the tail.
// SIMD pairing (wid%4): {rec1,p12} {rec2,p23} {rec3,pgi1} {recon,ppc2} - balanced.
__global__ __launch_bounds__(512, 1)
void fused_chain8(const float* __restrict__ c_btn, const float* __restrict__ hmp,
                  const float* __restrict__ We_ih, const float* __restrict__ be_ih,
                  const float* __restrict__ We_hh, const float* __restrict__ be_hh,
                  const float* __restrict__ Wm_ih, const float* __restrict__ bm_ih,
                  const float* __restrict__ Wm_hh, const float* __restrict__ bm_hh,
                  const float* __restrict__ Wd_ih, const float* __restrict__ bd_ih,
                  const float* __restrict__ Wd_hh, const float* __restrict__ bd_hh,
                  const float* __restrict__ W_dec, const float* __restrict__ b_dec,
                  const float* __restrict__ W_p1, const float* __restrict__ b_p1,
                  const float* __restrict__ W_p2, const float* __restrict__ b_p2,
                  float* __restrict__ recon, float* __restrict__ pred) {
  const int b = blockIdx.x, tid = threadIdx.x, wid = tid >> 6, g = tid & 63;
  __shared__ __align__(16) _Float16 cbuf[2][HH], mbuf[2][HH];
  __shared__ __align__(16) _Float16 h1h[2][HH], h2h[2][HH], h3h[2][HH];
  __shared__ __align__(16) float h3f[2][HH];
  __shared__ __align__(16) float q1[2][GG], q2a[2][GG], q2b[2][GG], q3[2][GG];
  __shared__ __align__(16) float h0s[HH], ps[HH];

  half2_t wa[32], wb[32], wc[32];   // 3 rows x 64 f16 (roles 0,1,2,4,5,6,7)
  float wdec[64];                   // recon row (fp32, role 3)
  float b0 = 0.f, b1 = 0.f, b2 = 0.f;   // accumulator init (gate / proj bias)
  float e0 = 0.f, e1 = 0.f, e2 = 0.f;   // rec3 extra bias (bd_ih)
  if (wid == 0) {
    loadroww_(wa, We_hh + (size_t)g * HH);
    loadroww_(wb, We_hh + (size_t)(g + 64) * HH);
    loadroww_(wc, We_hh + (size_t)(g + 128) * HH);
    b0 = be_hh[g]; b1 = be_hh[64 + g]; b2 = be_hh[128 + g];
  } else if (wid == 1) {
    loadroww_(wa, Wm_hh + (size_t)g * HH);
    loadroww_(wb, Wm_hh + (size_t)(g + 64) * HH);
    loadroww_(wc, Wm_hh + (size_t)(g + 128) * HH);
    b0 = bm_hh[g]; b1 = bm_hh[64 + g]; b2 = bm_hh[128 + g];
  } else if (wid == 2) {
    loadroww_(wa, Wd_hh + (size_t)g * HH);
    loadroww_(wb, Wd_hh + (size_t)(g + 64) * HH);
    loadroww_(wc, Wd_hh + (size_t)(g + 128) * HH);
    b0 = bd_hh[g]; b1 = bd_hh[64 + g]; b2 = bd_hh[128 + g];
    e0 = bd_ih[g]; e1 = bd_ih[64 + g]; e2 = bd_ih[128 + g];
  } else if (wid == 3) {
    loadrow_(wdec, W_dec + (size_t)g * HH);
    b0 = b_dec[g];
  } else if (wid == 4) {           // Wm_ih [192][128] cols 0..63
    loadroww_(wa, Wm_ih + (size_t)g * 128);
    loadroww_(wb, Wm_ih + (size_t)(g + 64) * 128);
    loadroww_(wc, Wm_ih + (size_t)(g + 128) * 128);
  } else if (wid == 5) {           // Wd_ih [192][64]
    loadroww_(wa, Wd_ih + (size_t)g * HH);
    loadroww_(wb, Wd_ih + (size_t)(g + 64) * HH);
    loadroww_(wc, Wd_ih + (size_t)(g + 128) * HH);
  } else if (wid == 6) {           // We_ih [192][64]
    loadroww_(wa, We_ih + (size_t)g * HH);
    loadroww_(wb, We_ih + (size_t)(g + 64) * HH);
    loadroww_(wc, We_ih + (size_t)(g + 128) * HH);
    b0 = be_ih[g]; b1 = be_ih[64 + g]; b2 = be_ih[128 + g];
  } else {                         // Wm_ih cols 64..127
    loadroww_(wa, Wm_ih + (size_t)g * 128 + 64);
    loadroww_(wb, Wm_ih + (size_t)(g + 64) * 128 + 64);
    loadroww_(wc, Wm_ih + (size_t)(g + 128) * 128 + 64);
    b0 = bm_ih[g]; b1 = bm_ih[64 + g]; b2 = bm_ih[128 + g];
  }

  if (wid == 0) {
    h1h[0][g] = (_Float16)0.f; h1h[1][g] = (_Float16)0.f;
    h2h[0][g] = (_Float16)0.f; h2h[1][g] = (_Float16)0.f;
    h3h[0][g] = (_Float16)0.f; h3h[1][g] = (_Float16)0.f;
  }
  // input staging preload (2 LDS slots + 2 in-register prefetch)
  const float* cb = c_btn + (size_t)b * TT * NN + g;
  const float* hm = hmp   + (size_t)b * TT * NN + g;
  float pf0 = 0.f, pf1 = 0.f;
  if (wid == 6) {
    cbuf[0][g] = (_Float16)cb[0]; cbuf[1][g] = (_Float16)cb[NN];
    pf0 = cb[2 * NN]; pf1 = cb[3 * NN];
  }
  if (wid == 7) {
    mbuf[0][g] = (_Float16)hm[0]; mbuf[1][g] = (_Float16)hm[NN];
    pf0 = hm[2 * NN]; pf1 = hm[3 * NN];
  }
  if (wid <= 2) __builtin_amdgcn_s_setprio(1);   // favor the rec critical chain
  __syncthreads();

  float hown = 0.f;
  for (int ph = 0; ph < TT + 6; ++ph) {
    const int pw = ph & 1, pr = pw ^ 1;
    if (wid == 6) {                 // gi1 = We_ih @ c[t] + be_ih, t = ph
      int t = ph;
      if (t < TT) {
        half2_t hp[32]; load_h16_(&cbuf[pw][0], hp);
        if (t + 2 < TT) cbuf[pw][g] = (_Float16)(pw ? pf1 : pf0);
        float a0 = b0, a1 = b1, a2 = b2;
        if (t + 4 < TT) { float nv = cb[(size_t)(t + 4) * NN]; if (pw) pf1 = nv; else pf0 = nv; }
        mvdot3_(hp, wa, wb, wc, a0, a1, a2);
        q1[pw][g] = a0; q1[pw][64 + g] = a1; q1[pw][128 + g] = a2;
      }
    } else if (wid == 0) {          // rec1, t = ph-1
      int t = ph - 1;
      if (t >= 0 && t < TT) {
        half2_t hp[32]; load_h16_(&h1h[pr][0], hp);
        float a0 = b0, a1 = b1, a2 = b2;
        mvdot3_(hp, wa, wb, wc, a0, a1, a2);
        float r = fsig_(q1[pr][g] + a0), z = fsig_(q1[pr][64 + g] + a1);
        float n = ftanh_(q1[pr][128 + g] + r * a2);
        hown = fmaf(z, hown - n, n);
        h1h[pw][g] = (_Float16)hown;
      }
    } else if (wid == 4) {          // q2a = Wm_ih[:,:64] @ h1[t], t = ph-2
      int t = ph - 2;
      if (t >= 0 && t < TT) {
        half2_t hp[32]; load_h16_(&h1h[pr][0], hp);
        float a0 = 0.f, a1 = 0.f, a2 = 0.f;
        mvdot3_(hp, wa, wb, wc, a0, a1, a2);
        q2a[pw][g] = a0; q2a[pw][64 + g] = a1; q2a[pw][128 + g] = a2;
      }
    } else if (wid == 7) {          // q2b = Wm_ih[:,64:] @ hmp[t] + bm_ih, t = ph-2
      int t = ph - 2;
      if (t >= 0 && t < TT) {
        half2_t hp[32]; load_h16_(&mbuf[pw][0], hp);
        if (t + 2 < TT) mbuf[pw][g] = (_Float16)(pw ? pf1 : pf0);
        float a0 = b0, a1 = b1, a2 = b2;
        if (t + 4 < TT) { float nv = hm[(size_t)(t + 4) * NN]; if (pw) pf1 = nv; else pf0 = nv; }
        mvdot3_(hp, wa, wb, wc, a0, a1, a2);
        q2b[pw][g] = a0; q2b[pw][64 + g] = a1; q2b[pw][128 + g] = a2;
      }
    } else if (wid == 1) {          // rec2, t = ph-3
      int t = ph - 3;
      if (t >= 0 && t < TT) {
        half2_t hp[32]; load_h16_(&h2h[pr][0], hp);
        float a0 = b0, a1 = b1, a2 = b2;
        mvdot3_(hp, wa, wb, wc, a0, a1, a2);
        float gr = q2a[pr][g] + q2b[pr][g];
        float gz = q2a[pr][64 + g] + q2b[pr][64 + g];
        float gn = q2a[pr][128 + g] + q2b[pr][128 + g];
        float r = fsig_(gr + a0), z = fsig_(gz + a1), n = ftanh_(gn + r * a2);
        hown = fmaf(z, hown - n, n);
        h2h[pw][g] = (_Float16)hown;
      }
    } else if (wid == 5) {          // q3 = Wd_ih @ h2[t], t = ph-4
      int t = ph - 4;
      if (t >= 0 && t < TT) {
        half2_t hp[32]; load_h16_(&h2h[pr][0], hp);
        float a0 = 0.f, a1 = 0.f, a2 = 0.f;
        mvdot3_(hp, wa, wb, wc, a0, a1, a2);
        q3[pw][g] = a0; q3[pw][64 + g] = a1; q3[pw][128 + g] = a2;
      }
    } else if (wid == 2) {          // rec3, t = ph-5
      int t = ph - 5;
      if (t >= 0 && t < TT) {
        half2_t hp[32]; load_h16_(&h3h[pr][0], hp);
        float a0 = b0, a1 = b1, a2 = b2;
        mvdot3_(hp, wa, wb, wc, a0, a1, a2);
        float r = fsig_(q3[pr][g] + e0 + a0), z = fsig_(q3[pr][64 + g] + e1 + a1);
        float n = ftanh_(q3[pr][128 + g] + e2 + r * a2);
        hown = fmaf(z, hown - n, n);
        h3h[pw][g] = (_Float16)hown;
        h3f[pw][g] = hown;
        if (t == 0) h0s[g] = hown;
      }
    } else {                        // wid==3: recon = W_dec @ h3[t] + b_dec, t = ph-6
      int t = ph - 6;
      if (t >= 0) {
        const float4* h4 = (const float4*)&h3f[pr][0];
        float a0 = b0, a1 = 0.f;
        #pragma unroll
        for (int i = 0; i < 8; ++i) {
          float4 hv = h4[2 * i], hw = h4[2 * i + 1];
          a0 = fmaf(hv.x, wdec[8*i],   fmaf(hv.y, wdec[8*i+1], fmaf(hv.z, wdec[8*i+2], fmaf(hv.w, wdec[8*i+3], a0))));
          a1 = fmaf(hw.x, wdec[8*i+4], fmaf(hw.y, wdec[8*i+5], fmaf(hw.z, wdec[8*i+6], fmaf(hw.w, wdec[8*i+7], a1))));
        }
        recon[((size_t)b * TT + t) * NN + g] = a0 + a1;
      }
    }
    PIPE_BARRIER();
  }

  // pred head (wave 0 only; h0s written at phase 5, synced by loop barriers)
  if (wid == 0) {
    float w1r[64]; loadrow_(w1r, W_p1 + (size_t)g * HH);
    const float4* h4 = (const float4*)&h0s[0];
    float a = b_p1[g];
    #pragma unroll
    for (int i = 0; i < 16; ++i) {
      float4 hv = h4[i];
      a = fmaf(hv.x, w1r[4*i], fmaf(hv.y, w1r[4*i+1], fmaf(hv.z, w1r[4*i+2], fmaf(hv.w, w1r[4*i+3], a))));
    }
    ps[g] = fmaxf(a, 0.f);
    asm volatile("s_waitcnt lgkmcnt(0)" ::: "memory");
    float w2r[64]; loadrow_(w2r, W_p2 + (size_t)g * HH);
    const float4* p4 = (const float4*)&ps[0];
    float c2 = b_p2[g];
    #pragma unroll
    for (int i = 0; i < 16; ++i) {
      float4 pv = p4[i];
      c2 = fmaf(pv.x, w2r[4*i], fmaf(pv.y, w2r[4*i+1], fmaf(pv.z, w2r[4*i+2], fmaf(pv.w, w2r[4*i+3], c2))));
    }
    pred[(size_t)b * NN + g] = c2;
  }
}

extern "C" void kernel_launch(void* const* d_in, const int* in_sizes, int n_in,
                              void* d_out, int out_size, void* d_ws, size_t ws_size,
                              hipStream_t stream) {
  const float* x      = (const float*)d_in[0];
  const float* conv_w = (const float*)d_in[2];
  const float* conv_b = (const float*)d_in[3];
  const float* We_ih  = (const float*)d_in[4];
  const float* We_hh  = (const float*)d_in[5];
  const float* be_ih  = (const float*)d_in[6];
  const float* be_hh  = (const float*)d_in[7];
  const float* Ww     = (const float*)d_in[8];
  const float* bw     = (const float*)d_in[9];
  const float* Wa     = (const float*)d_in[10];
  const float* ba     = (const float*)d_in[11];
  const float* Wm_ih  = (const float*)d_in[12];
  const float* Wm_hh  = (const float*)d_in[13];
  const float* bm_ih  = (const float*)d_in[14];
  const float* bm_hh  = (const float*)d_in[15];
  const float* Wd_ih  = (const float*)d_in[16];
  const float* Wd_hh  = (const float*)d_in[17];
  const float* bd_ih  = (const float*)d_in[18];
  const float* bd_hh  = (const float*)d_in[19];
  const float* W_dec  = (const float*)d_in[20];
  const float* b_dec  = (const float*)d_in[21];
  const float* W_p1   = (const float*)d_in[22];
  const float* b_p1   = (const float*)d_in[23];
  const float* W_p2   = (const float*)d_in[24];
  const float* b_p2   = (const float*)d_in[25];
  float* out = (float*)d_out;

  float* wsf   = (float*)d_ws;
  float* c_nt  = wsf;                 // B*N*T    = 524288
  float* c_btn = c_nt  + 524288;      // B*T*N    = 524288
  float* s1    = c_btn + 524288;      // B*N*E    = 524288
  float* s2    = s1    + 524288;      // B*N*E    = 524288
  float* hmp   = s2    + 524288;      // B*T*N    = 524288

  conv_selu_kernel<<<dim3(8, BB), 128, 0, stream>>>(x, conv_w, conv_b, c_nt, c_btn);
  s12_kernel<<<BB * NN / 16, 128, 0, stream>>>(c_nt, Ww, s1, s2);
  gat_kernel<<<dim3(NN, BB), 128, 0, stream>>>(s1, s2, bw, Wa, ba, c_nt, hmp);
  // fused 8-wave pipeline: projections + 3 GRUs + recon + pred head
  fused_chain8<<<BB, 512, 0, stream>>>(c_btn, hmp,
                                       We_ih, be_ih, We_hh, be_hh,
                                       Wm_ih, bm_ih, Wm_hh, bm_hh,
                                       Wd_ih, bd_ih, Wd_hh, bd_hh,
                                       W_dec, b_dec, W_p1, b_p1, W_p2, b_p2,
                                       out, out + BB * TT * NN);
}